// Round 6
// baseline (1316.843 us; speedup 1.0000x reference)
//
#include <hip/hip_runtime.h>
#include <math.h>

typedef unsigned short ushort_t;
typedef unsigned int uint_t;
typedef unsigned long long u64_t;
typedef __attribute__((ext_vector_type(8))) short short8;
typedef __attribute__((ext_vector_type(4))) float f32x4;

#define N_NODES 8192
#define DIM 512
#define KTOT 1024
#define NCOLS 4096
#define BM 128
#define BN 128
#define NTILE (NCOLS / BN)   // 32 column tiles
#define KIT (KTOT / 32)      // 32 k iterations (BK=32)
#define XRB (N_NODES / BM)   // 64 position rowblocks
#define XTILES (XRB * NTILE) // 2048 x tasks
#define WIMG_USHORTS ((size_t)NTILE * KIT * 8192)
#define MAXLEV_LDS 512

__device__ __forceinline__ float sigm(float x) { return 1.0f / (1.0f + __expf(-x)); }
__device__ __forceinline__ float tanh_fast(float x) {
    float ax = fabsf(x);
    float e = __expf(2.0f * ax);
    float t = 1.0f - 2.0f / (e + 1.0f);
    return copysignf(t, x);
}
__device__ __forceinline__ uint_t packf(float f) {
    uint_t u = __float_as_uint(f);
    uint_t hi = u & 0xffff0000u;
    float r = f - __uint_as_float(hi);
    return hi | (__float_as_uint(r) >> 16);
}
__device__ __forceinline__ float unpackf(uint_t w) {
    return __uint_as_float(w & 0xffff0000u) + __uint_as_float(w << 16);
}

// ---------------------------------------------------------------------------
// Prep: weights -> split bf16 (hi+lo) LDS-image layout. (verified r2-r5)
// ---------------------------------------------------------------------------
__global__ void __launch_bounds__(256) prep_wimg_kernel(
    const float* __restrict__ Wx_iou_v, const float* __restrict__ Wh_iou_v,
    const float* __restrict__ Wx_f_v,   const float* __restrict__ Wh_f_v,
    const float* __restrict__ Wx_iou_l, const float* __restrict__ Wh_iou_l,
    const float* __restrict__ Wx_f_l,   const float* __restrict__ Wh_f_l,
    ushort_t* __restrict__ Wimg)
{
    __shared__ float T[32][132];
    int p = blockIdx.x >> 5, it = blockIdx.x & 31;
    int tid = threadIdx.x;
#pragma unroll
    for (int e = 0; e < 16; ++e) {
        int lin = e * 256 + tid;
        int dloc = lin & 15, kk = (lin >> 4) & 31, q = lin >> 9;
        int d = p * 16 + dloc;
        int qq = q & 3; bool lang = q >= 4;
        int k = it * 32 + kk;
        const float* W; int col, stride;
        if (qq < 3) { col = qq * DIM + d; stride = 3 * DIM;
            W = (k < DIM) ? (lang ? Wx_iou_l : Wx_iou_v) : (lang ? Wh_iou_l : Wh_iou_v); }
        else        { col = d; stride = DIM;
            W = (k < DIM) ? (lang ? Wx_f_l : Wx_f_v) : (lang ? Wh_f_l : Wh_f_v); }
        int kr = (k < DIM) ? k : (k - DIM);
        T[kk][dloc * 8 + q] = W[(size_t)kr * stride + col];
    }
    __syncthreads();
    size_t tilebase = (size_t)blockIdx.x * 8192;
#pragma unroll
    for (int gch = 0; gch < 4; ++gch) {
        int gi = gch * 256 + tid;
        int plane = gi >> 9, col = (gi >> 2) & 127, gp = gi & 3;
        int gd = gp ^ (col & 3);
        uint_t wds[4];
#pragma unroll
        for (int i = 0; i < 4; ++i) {
            float f0 = T[gd * 8 + 2 * i][col];
            float f1 = T[gd * 8 + 2 * i + 1][col];
            uint_t u0 = __float_as_uint(f0), u1 = __float_as_uint(f1);
            uint_t h0 = u0 & 0xffff0000u, h1 = u1 & 0xffff0000u;
            uint_t v0, v1;
            if (plane == 0) { v0 = h0 >> 16; v1 = h1; }
            else {
                float r0 = f0 - __uint_as_float(h0), r1 = f1 - __uint_as_float(h1);
                v0 = __float_as_uint(r0) >> 16; v1 = __float_as_uint(r1) & 0xffff0000u;
            }
            wds[i] = v1 | v0;
        }
        *(uint4*)(Wimg + tilebase + (size_t)gi * 8) = make_uint4(wds[0], wds[1], wds[2], wds[3]);
    }
}

__global__ void prep_bias_kernel(
    const float* __restrict__ bx_iou_v, const float* __restrict__ bh_iou_v,
    const float* __restrict__ bx_f_v,   const float* __restrict__ bh_f_v,
    const float* __restrict__ bx_iou_l, const float* __restrict__ bh_iou_l,
    const float* __restrict__ bx_f_l,   const float* __restrict__ bh_f_l,
    float* __restrict__ bias)
{
    int j = blockIdx.x * blockDim.x + threadIdx.x;
    if (j >= NCOLS) return;
    int d = j >> 3, q = j & 7;
    int qq = q & 3;
    bool lang = (q & 4) != 0;
    const float* bx; const float* bh; int col;
    if (qq < 3) { col = qq * DIM + d; bx = lang ? bx_iou_l : bx_iou_v; bh = lang ? bh_iou_l : bh_iou_v; }
    else        { col = d;            bx = lang ? bx_f_l  : bx_f_v;   bh = lang ? bh_f_l  : bh_f_v; }
    bias[j] = bx[col] + bh[col];
}

// ---------------------------------------------------------------------------
// Level computation + counting sort (verified r2-r5; rb tables dropped)
// ---------------------------------------------------------------------------
__global__ void __launch_bounds__(1024) levels_sort_kernel(
    const int* __restrict__ parent,
    int* __restrict__ order, int* __restrict__ offsets,
    int* __restrict__ counts, int* __restrict__ cursors,
    int* __restrict__ nlev, int* __restrict__ tilestart)
{
    __shared__ int s_level[N_NODES];
    __shared__ int s_assigned;
    __shared__ int s_maxlev;
    int tid = threadIdx.x;
    int pr[8];
#pragma unroll
    for (int ii = 0; ii < 8; ++ii) {
        int i = tid + ii * 1024;
        pr[ii] = parent[i];
        s_level[i] = -1;
    }
    for (int i = tid; i <= N_NODES; i += 1024) counts[i] = 0;
    if (tid == 0) { s_assigned = 0; s_maxlev = 0; }
    __syncthreads();

    for (int pass = 0; pass <= N_NODES; ++pass) {
        int newly = 0;
#pragma unroll
        for (int ii = 0; ii < 8; ++ii) {
            int i = tid + ii * 1024;
            if (s_level[i] < 0) {
                int p = pr[ii];
                if (p == 0) { s_level[i] = 0; newly++; }
                else { int lp = s_level[p - 1]; if (lp >= 0) { s_level[i] = lp + 1; newly++; } }
            }
        }
        if (newly) atomicAdd(&s_assigned, newly);
        __syncthreads();
        int a = s_assigned;
        if (a >= N_NODES) break;
        __syncthreads();
    }

#pragma unroll
    for (int ii = 0; ii < 8; ++ii) {
        int i = tid + ii * 1024;
        int lv = s_level[i];
        atomicAdd(&counts[lv], 1);
        atomicMax(&s_maxlev, lv);
    }
    __syncthreads();
    if (tid == 0) {
        int nl = s_maxlev + 1;
        nlev[0] = nl;
        int off = 0, toff = 0;
        for (int l = 0; l < nl; ++l) {
            offsets[l] = off; cursors[l] = off; tilestart[l] = toff;
            toff += ((counts[l] + BM - 1) / BM) * NTILE;
            off += counts[l];
        }
        offsets[nl] = off;
        tilestart[nl] = toff;
        nlev[1] = toff;   // total h-tiles
    }
    __syncthreads();
#pragma unroll
    for (int ii = 0; ii < 8; ++ii) {
        int i = tid + ii * 1024;
        int pos = atomicAdd(&cursors[s_level[i]], 1);
        order[pos] = i;
    }
}

// ---------------------------------------------------------------------------
// Staging helpers
// ---------------------------------------------------------------------------
__device__ __forceinline__ void writeA_words(int tid, ushort_t* Ab,
                                             const uint_t* hw, const uint_t* lw)
{
    int row = tid >> 1, h16 = tid & 1;
    int gd0 = h16 * 2, gd1 = gd0 + 1, rs = row & 3;
    ushort_t* base = Ab + row * 32;
    *(uint4*)(base + (gd0 ^ rs) * 8)        = make_uint4(hw[0], hw[1], hw[2], hw[3]);
    *(uint4*)(base + (gd1 ^ rs) * 8)        = make_uint4(hw[4], hw[5], hw[6], hw[7]);
    *(uint4*)(base + 4096 + (gd0 ^ rs) * 8) = make_uint4(lw[0], lw[1], lw[2], lw[3]);
    *(uint4*)(base + 4096 + (gd1 ^ rs) * 8) = make_uint4(lw[4], lw[5], lw[6], lw[7]);
}

__device__ __forceinline__ void writeA_lds(int tid, ushort_t* Ab, const float* f)
{
    uint_t hw[8], lw[8];
#pragma unroll
    for (int i = 0; i < 8; ++i) {
        float f0 = f[2 * i], f1 = f[2 * i + 1];
        uint_t u0 = __float_as_uint(f0), u1 = __float_as_uint(f1);
        uint_t h0 = u0 & 0xffff0000u, h1 = u1 & 0xffff0000u;
        float r0 = f0 - __uint_as_float(h0), r1 = f1 - __uint_as_float(h1);
        hw[i] = h1 | (h0 >> 16);
        lw[i] = (__float_as_uint(r1) & 0xffff0000u) | (__float_as_uint(r0) >> 16);
    }
    writeA_words(tid, Ab, hw, lw);
}

// x-side A: gather inputs rows by level-sorted position (node from s_node)
__device__ __forceinline__ void loadA_xg(int it, int tid, const int* s_node,
    const float* __restrict__ inputs, float* f)
{
    int row = tid >> 1, h16 = tid & 1;
    int node = s_node[row];
    const float* base = inputs + (size_t)node * DIM + it * 32 + h16 * 16;
#pragma unroll
    for (int q4 = 0; q4 < 4; ++q4) {
        float4 v = *(const float4*)(base + q4 * 4);
        f[q4 * 4 + 0] = v.x; f[q4 * 4 + 1] = v.y; f[q4 * 4 + 2] = v.z; f[q4 * 4 + 3] = v.w;
    }
}

// h-side A from packed hi|lo u32 rows
__device__ __forceinline__ void loadA_hpack(int it, int tid,
    const int* s_node, const int* s_par,
    const uint_t* __restrict__ hPack, uint_t* hw, uint_t* lw)
{
    int row = tid >> 1, h16 = tid & 1;
    int p = (s_node[row] >= 0) ? s_par[row] : 0;
    uint_t u[16];
    if (p > 0) {
        const uint4* base = (const uint4*)(hPack + (size_t)(p - 1) * DIM + (it - 16) * 32 + h16 * 16);
#pragma unroll
        for (int q4 = 0; q4 < 4; ++q4) {
            uint4 v = base[q4];
            u[q4 * 4] = v.x; u[q4 * 4 + 1] = v.y; u[q4 * 4 + 2] = v.z; u[q4 * 4 + 3] = v.w;
        }
    } else {
#pragma unroll
        for (int i = 0; i < 16; ++i) u[i] = 0;
    }
#pragma unroll
    for (int i = 0; i < 8; ++i) {
        hw[i] = (u[2 * i + 1] & 0xffff0000u) | (u[2 * i] >> 16);
        lw[i] = (u[2 * i + 1] << 16) | (u[2 * i] & 0xffffu);
    }
}

__device__ __forceinline__ void loadB_regs(int it, int ntile, int tid,
                                           const ushort_t* __restrict__ Wimg, uint4* br)
{
    const uint4* g = (const uint4*)(Wimg + ((size_t)(ntile * KIT + it)) * 8192);
#pragma unroll
    for (int j = 0; j < 4; ++j) br[j] = g[(size_t)tid + 256 * j];
}

__device__ __forceinline__ void writeB_lds(int tid, ushort_t* Bb, const uint4* br)
{
    uint4* d = (uint4*)Bb;
#pragma unroll
    for (int j = 0; j < 4; ++j) d[tid + 256 * j] = br[j];
}

__device__ __forceinline__ void mfma_phase(const ushort_t* Ab, const ushort_t* Bb,
                                           int wr, int wc, int lane, f32x4 acc[4][4])
{
    int l15 = lane & 15, g = lane >> 4;
    short8 ah[4], al[4];
#pragma unroll
    for (int m = 0; m < 4; ++m) {
        int row = wr * 64 + m * 16 + l15;
        const ushort_t* pa = Ab + row * 32 + ((g ^ (row & 3)) * 8);
        ah[m] = *(const short8*)pa;
        al[m] = *(const short8*)(pa + 4096);
    }
#pragma unroll
    for (int n = 0; n < 4; ++n) {
        int col = wc * 64 + n * 16 + l15;
        const ushort_t* pb = Bb + col * 32 + ((g ^ (col & 3)) * 8);
        short8 bh = *(const short8*)pb;
        short8 bl = *(const short8*)(pb + 4096);
#pragma unroll
        for (int m = 0; m < 4; ++m) {
            acc[m][n] = __builtin_amdgcn_mfma_f32_16x16x32_bf16(ah[m], bh, acc[m][n], 0, 0, 0);
            acc[m][n] = __builtin_amdgcn_mfma_f32_16x16x32_bf16(al[m], bh, acc[m][n], 0, 0, 0);
            acc[m][n] = __builtin_amdgcn_mfma_f32_16x16x32_bf16(ah[m], bl, acc[m][n], 0, 0, 0);
        }
    }
}

// ---------------------------------------------------------------------------
// Worker kernel: x-workers (blockIdx < grid/4) pop x-tiles (position-ordered),
// then everyone pops h-tiles. Level-granular counters, 1-thread polling.
// ---------------------------------------------------------------------------
__global__ void __launch_bounds__(256, 2) tree_lv_kernel(
    const float* __restrict__ inputs, const float* __restrict__ type_mask,
    const ushort_t* __restrict__ Wimg, const float* __restrict__ bias,
    const int* __restrict__ order, const int* __restrict__ offsets,
    const int* __restrict__ nlev, const int* __restrict__ parent,
    const int* __restrict__ tilestart, int* __restrict__ ctr,
    float* __restrict__ preAct, uint_t* __restrict__ hPack, uint_t* __restrict__ cPack,
    float* __restrict__ out)
{
    float* cOut = out;
    float* hOut = out + (size_t)N_NODES * DIM;

    __shared__ __align__(16) ushort_t sm16[32768];   // A0,A1,B0,B1 (16KB each)
    __shared__ int s_node[BM];
    __shared__ int s_par[BM];
    __shared__ float s_tm[BM][2];
    __shared__ int s_ts[MAXLEV_LDS];
    __shared__ int s_off[MAXLEV_LDS];
    __shared__ int s_t;

    int tid = threadIdx.x;
    int lane = tid & 63, w = tid >> 6, wr = w >> 1, wc = w & 1;
    int l15 = lane & 15, g = lane >> 4;
    int nl = nlev[0];
    int totalH = nlev[1];

    int* xCur   = ctr;
    int* hCur   = ctr + 1;
    int* levCnt = ctr + 8;
    int* xDone  = ctr + 8 + MAXLEV_LDS;

    int nload = nl + 1; if (nload > MAXLEV_LDS) nload = MAXLEV_LDS;
    for (int i = tid; i < nload; i += 256) { s_ts[i] = tilestart[i]; s_off[i] = offsets[i]; }
    __syncthreads();

    // ================= x-worker phase =================
    if (blockIdx.x < (gridDim.x >> 2)) {
        for (;;) {
            if (tid == 0)
                s_t = __hip_atomic_fetch_add(xCur, 1, __ATOMIC_RELAXED, __HIP_MEMORY_SCOPE_AGENT);
            __syncthreads();
            int t = s_t;
            if (t >= XTILES) break;
            int prb = t >> 5, ntile = t & 31;
            int jc = ntile * BN, pos0 = prb * BM;

            if (tid < BM) s_node[tid] = order[pos0 + tid];
            __syncthreads();

            f32x4 acc[4][4];
#pragma unroll
            for (int m = 0; m < 4; ++m)
#pragma unroll
                for (int n = 0; n < 4; ++n) acc[m][n] = (f32x4)(0.f);

            {
                float fA[16]; uint4 br[4];
                loadA_xg(0, tid, s_node, inputs, fA);
                loadB_regs(0, ntile, tid, Wimg, br);
                writeA_lds(tid, sm16, fA);
                writeB_lds(tid, sm16 + 16384, br);
            }
            __syncthreads();
            int cur = 0;
            for (int it = 0; it < 16; ++it) {
                float fA[16]; uint4 br[4];
                bool hn = it < 15;
                if (hn) {
                    loadA_xg(it + 1, tid, s_node, inputs, fA);
                    loadB_regs(it + 1, ntile, tid, Wimg, br);
                }
                __builtin_amdgcn_s_setprio(1);
                mfma_phase(sm16 + cur * 8192, sm16 + 16384 + cur * 8192, wr, wc, lane, acc);
                __builtin_amdgcn_s_setprio(0);
                if (hn) {
                    writeA_lds(tid, sm16 + (cur ^ 1) * 8192, fA);
                    writeB_lds(tid, sm16 + 16384 + (cur ^ 1) * 8192, br);
                }
                __syncthreads();
                cur ^= 1;
            }

            // transpose + contiguous 8B sc1 stores to preAct (position-major)
            float* eps = (float*)sm16;
#pragma unroll
            for (int pass = 0; pass < 2; ++pass) {
                if (wc == pass) {
#pragma unroll
                    for (int m = 0; m < 4; ++m)
#pragma unroll
                        for (int n = 0; n < 4; ++n) {
                            int row = wr * 64 + m * 16 + g * 4;
                            int c = n * 16 + l15;
#pragma unroll
                            for (int r = 0; r < 4; ++r) eps[(row + r) * 68 + c] = acc[m][n][r];
                        }
                }
                __syncthreads();
#pragma unroll
                for (int e = 0; e < 4; ++e) {
                    int task = e * 256 + tid;
                    int row = task >> 3, dl = task & 7;
                    const float* ep = &eps[row * 68 + dl * 8];
                    u64_t* dst = (u64_t*)(preAct + (size_t)(pos0 + row) * NCOLS + jc + pass * 64 + dl * 8);
#pragma unroll
                    for (int k2 = 0; k2 < 4; ++k2) {
                        u64_t v = ((u64_t)__float_as_uint(ep[2 * k2 + 1]) << 32)
                                | (u64_t)__float_as_uint(ep[2 * k2]);
                        __hip_atomic_store(dst + k2, v, __ATOMIC_RELAXED, __HIP_MEMORY_SCOPE_AGENT);
                    }
                }
                __syncthreads();
            }

            __builtin_amdgcn_s_waitcnt(0);
            __syncthreads();
            if (tid == 0)
                __hip_atomic_store(&xDone[t], 1, __ATOMIC_RELAXED, __HIP_MEMORY_SCOPE_AGENT);
            __syncthreads();
        }
    }

    // ================= h phase (all blocks) =================
    for (;;) {
        if (tid == 0)
            s_t = __hip_atomic_fetch_add(hCur, 1, __ATOMIC_RELAXED, __HIP_MEMORY_SCOPE_AGENT);
        __syncthreads();
        int t2 = s_t;
        if (t2 >= totalH) break;

        int lev = 0;
        while (lev + 1 < nload && s_ts[lev + 1] <= t2) ++lev;
        int lt = t2 - s_ts[lev];
        int ntile = lt % NTILE;
        int mt = lt / NTILE;
        int start = s_off[lev];
        int cnt = s_off[lev + 1] - start;
        int jc = ntile * BN;
        int r0 = mt * BM;
        int cntloc = cnt - r0; if (cntloc > BM) cntloc = BM;

        if (tid < BM) {
            int r = r0 + tid;
            int node = (r < cnt) ? order[start + r] : -1;
            s_node[tid] = node;
            int p = (node >= 0) ? parent[node] : 0;
            s_par[tid] = p;
            float t0 = 0.f, t1 = 0.f;
            if (node >= 0) { t0 = type_mask[node * 2]; t1 = type_mask[node * 2 + 1]; }
            s_tm[tid][0] = t0; s_tm[tid][1] = t1;
        }
        __syncthreads();

        f32x4 acc[4][4];
#pragma unroll
        for (int m = 0; m < 4; ++m)
#pragma unroll
            for (int n = 0; n < 4; ++n) acc[m][n] = (f32x4)(0.f);

        if (lev > 0) {
            // ---- wait: previous level fully published (single poller)
            int ntlPrev = s_ts[lev] - s_ts[lev - 1];
            if (tid == 0) {
                while (__hip_atomic_load(&levCnt[lev - 1], __ATOMIC_RELAXED,
                                         __HIP_MEMORY_SCOPE_AGENT) < ntlPrev)
                    __builtin_amdgcn_s_sleep(2);
            }
            __syncthreads();

            // ---- h-GEMM K=512, depth-2 prefetch (fully unrolled, static idx)
            uint_t hws[2][8], lws[2][8]; uint4 brs[2][4];
            loadA_hpack(16, tid, s_node, s_par, hPack, hws[0], lws[0]);
            loadB_regs(16, ntile, tid, Wimg, brs[0]);
            writeA_words(tid, sm16, hws[0], lws[0]);
            writeB_lds(tid, sm16 + 16384, brs[0]);
            loadA_hpack(17, tid, s_node, s_par, hPack, hws[1], lws[1]);
            loadB_regs(17, ntile, tid, Wimg, brs[1]);
            __syncthreads();
#pragma unroll
            for (int k = 16; k < 32; ++k) {
                const int cur = (k - 16) & 1, nxt = cur ^ 1;
                if (k + 2 < 32) {
                    loadA_hpack(k + 2, tid, s_node, s_par, hPack, hws[cur], lws[cur]);
                    loadB_regs(k + 2, ntile, tid, Wimg, brs[cur]);
                }
                __builtin_amdgcn_s_setprio(1);
                mfma_phase(sm16 + cur * 8192, sm16 + 16384 + cur * 8192, wr, wc, lane, acc);
                __builtin_amdgcn_s_setprio(0);
                if (k + 1 < 32) {
                    writeA_words(tid, sm16 + nxt * 8192, hws[nxt], lws[nxt]);
                    writeB_lds(tid, sm16 + 16384 + nxt * 8192, brs[nxt]);
                }
                __syncthreads();
            }
        }

        // ---- wait for own preAct x-tiles (1-2 flags, single poller)
        {
            int prb0 = (start + r0) >> 7;
            int prb1 = (start + r0 + cntloc - 1) >> 7;
            if (tid == 0) {
                while (__hip_atomic_load(&xDone[prb0 * NTILE + ntile], __ATOMIC_RELAXED,
                                         __HIP_MEMORY_SCOPE_AGENT) == 0)
                    __builtin_amdgcn_s_sleep(2);
                if (prb1 != prb0)
                    while (__hip_atomic_load(&xDone[prb1 * NTILE + ntile], __ATOMIC_RELAXED,
                                             __HIP_MEMORY_SCOPE_AGENT) == 0)
                        __builtin_amdgcn_s_sleep(2);
            }
            __syncthreads();
        }

        // ---- epilogue: batched loads + acc transpose + LSTM cell
        float* eps = (float*)sm16;
#pragma unroll
        for (int pass = 0; pass < 2; ++pass) {
            // (1) issue global loads early (independent of eps)
            float4 P0[4], P1[4]; float CP[4];
#pragma unroll
            for (int e = 0; e < 4; ++e) {
                int task = e * 256 + tid;
                int row = task >> 3, dl = task & 7;
                P0[e] = make_float4(0.f, 0.f, 0.f, 0.f);
                P1[e] = P0[e]; CP[e] = 0.f;
                if (row < cntloc) {
                    int jb = jc + pass * 64 + dl * 8;
                    const float* pa = preAct + (size_t)(start + r0 + row) * NCOLS + jb;
                    P0[e] = *(const float4*)pa;
                    P1[e] = *(const float4*)(pa + 4);
                    int p = s_par[row];
                    if (p > 0) CP[e] = unpackf(cPack[(size_t)(p - 1) * DIM + (jb >> 3)]);
                }
            }
            // (2) transpose this pass's acc quadrant into LDS
            if (wc == pass) {
#pragma unroll
                for (int m = 0; m < 4; ++m)
#pragma unroll
                    for (int n = 0; n < 4; ++n) {
                        int row = wr * 64 + m * 16 + g * 4;
                        int c = n * 16 + l15;
#pragma unroll
                        for (int r = 0; r < 4; ++r) eps[(row + r) * 68 + c] = acc[m][n][r];
                    }
            }
            __syncthreads();
            // (3) compute + store
#pragma unroll
            for (int e = 0; e < 4; ++e) {
                int task = e * 256 + tid;
                int row = task >> 3, dl = task & 7;
                if (row < cntloc) {
                    int node = s_node[row];
                    const float* ep = &eps[row * 68 + dl * 8];
                    float4 v0 = *(const float4*)ep;
                    float4 v1 = *(const float4*)(ep + 4);
                    int jb = jc + pass * 64 + dl * 8;
                    float4 b0 = *(const float4*)(bias + jb);
                    float4 b1 = *(const float4*)(bias + jb + 4);
                    int d = jb >> 3;
                    float cp = CP[e];
                    float cv = sigm(v0.x + P0[e].x + b0.x) * tanh_fast(v0.z + P0[e].z + b0.z)
                             + sigm(v0.w + P0[e].w + b0.w) * cp;
                    float hv = sigm(v0.y + P0[e].y + b0.y) * tanh_fast(cv);
                    float cl = sigm(v1.x + P1[e].x + b1.x) * tanh_fast(v1.z + P1[e].z + b1.z)
                             + sigm(v1.w + P1[e].w + b1.w) * cp;
                    float hl = sigm(v1.y + P1[e].y + b1.y) * tanh_fast(cl);
                    float tm0 = s_tm[row][0], tm1 = s_tm[row][1];
                    float cn = tm0 * cl + tm1 * cv;
                    float hn2 = tm0 * hl + tm1 * hv;
                    size_t oi = (size_t)node * DIM + d;
                    cOut[oi] = cn;
                    hOut[oi] = hn2;
                    __hip_atomic_store(&cPack[oi], packf(cn),
                                       __ATOMIC_RELAXED, __HIP_MEMORY_SCOPE_AGENT);
                    __hip_atomic_store(&hPack[oi], packf(hn2),
                                       __ATOMIC_RELAXED, __HIP_MEMORY_SCOPE_AGENT);
                }
            }
            __syncthreads();
        }

        __builtin_amdgcn_s_waitcnt(0);
        __syncthreads();
        if (tid == 0)
            __hip_atomic_fetch_add(&levCnt[lev], 1, __ATOMIC_RELAXED, __HIP_MEMORY_SCOPE_AGENT);
        __syncthreads();
    }
}

// ---------------------------------------------------------------------------
extern "C" void kernel_launch(void* const* d_in, const int* in_sizes, int n_in,
                              void* d_out, int out_size, void* d_ws, size_t ws_size,
                              hipStream_t stream) {
    const float* inputs      = (const float*)d_in[0];
    const float* type_mask   = (const float*)d_in[1];
    const int*   parent      = (const int*)d_in[2];
    const float* W_ioux_vis  = (const float*)d_in[3];
    const float* b_ioux_vis  = (const float*)d_in[4];
    const float* W_iouh_vis  = (const float*)d_in[5];
    const float* b_iouh_vis  = (const float*)d_in[6];
    const float* W_fx_vis    = (const float*)d_in[7];
    const float* b_fx_vis    = (const float*)d_in[8];
    const float* W_fh_vis    = (const float*)d_in[9];
    const float* b_fh_vis    = (const float*)d_in[10];
    const float* W_ioux_lang = (const float*)d_in[11];
    const float* b_ioux_lang = (const float*)d_in[12];
    const float* W_iouh_lang = (const float*)d_in[13];
    const float* b_iouh_lang = (const float*)d_in[14];
    const float* W_fx_lang   = (const float*)d_in[15];
    const float* b_fx_lang   = (const float*)d_in[16];
    const float* W_fh_lang   = (const float*)d_in[17];
    const float* b_fh_lang   = (const float*)d_in[18];

    ushort_t* Wimg = (ushort_t*)d_ws;                      // 16 MB
    float* bias    = (float*)(Wimg + WIMG_USHORTS);
    int* order     = (int*)(bias + NCOLS);
    int* offsets   = order + N_NODES;
    int* counts    = offsets + (N_NODES + 2);
    int* cursors   = counts + (N_NODES + 2);
    int* nlev      = cursors + (N_NODES + 2);
    int* tilestart = nlev + 8;
    int* ctr       = tilestart + (N_NODES + 2);
    const int CTRN = 8 + MAXLEV_LDS + XTILES;
    size_t off2 = (size_t)((char*)(ctr + CTRN) - (char*)d_ws);
    off2 = (off2 + 255) & ~(size_t)255;
    uint_t* hPack = (uint_t*)((char*)d_ws + off2);                       // 16 MB
    uint_t* cPack = hPack + (size_t)N_NODES * DIM;                       // 16 MB
    float* preAct = (float*)(cPack + (size_t)N_NODES * DIM);             // 128 MB

    float* out = (float*)d_out;

    hipMemsetAsync((void*)ctr, 0, CTRN * sizeof(int), stream);

    hipLaunchKernelGGL(prep_wimg_kernel, dim3(NTILE * KIT), dim3(256), 0, stream,
                       W_ioux_vis, W_iouh_vis, W_fx_vis, W_fh_vis,
                       W_ioux_lang, W_iouh_lang, W_fx_lang, W_fh_lang, Wimg);
    hipLaunchKernelGGL(prep_bias_kernel, dim3(NCOLS / 256), dim3(256), 0, stream,
                       b_ioux_vis, b_iouh_vis, b_fx_vis, b_fh_vis,
                       b_ioux_lang, b_iouh_lang, b_fx_lang, b_fh_lang, bias);
    hipLaunchKernelGGL(levels_sort_kernel, dim3(1), dim3(1024), 0, stream,
                       parent, order, offsets, counts, cursors, nlev, tilestart);

    int occ = 0;
    if (hipOccupancyMaxActiveBlocksPerMultiprocessor(&occ, (const void*)tree_lv_kernel, 256, 0) != hipSuccess || occ < 1)
        occ = 1;
    int bpc = occ < 2 ? occ : 2;
    dim3 grid(256 * bpc);

    void* args[] = { (void*)&inputs, (void*)&type_mask, (void*)&Wimg, (void*)&bias,
                     (void*)&order, (void*)&offsets, (void*)&nlev, (void*)&parent,
                     (void*)&tilestart, (void*)&ctr,
                     (void*)&preAct, (void*)&hPack, (void*)&cPack, (void*)&out };
    hipLaunchCooperativeKernel((const void*)tree_lv_kernel, grid, dim3(256), args, 0, stream);
}

// Round 7
// 1108.935 us; speedup vs baseline: 1.1875x; 1.1875x over previous
//
#include <hip/hip_runtime.h>
#include <math.h>

typedef unsigned short ushort_t;
typedef unsigned int uint_t;
typedef unsigned long long u64_t;
typedef __attribute__((ext_vector_type(8))) short short8;
typedef __attribute__((ext_vector_type(4))) float f32x4;

#define N_NODES 8192
#define DIM 512
#define KTOT 1024
#define NCOLS 4096
#define BM 128
#define BN 128
#define NTILE (NCOLS / BN)   // 32 column tiles
#define KIT (KTOT / 32)      // 32 k iterations (BK=32)
#define XRB (N_NODES / BM)   // 64 node rowblocks
#define XTILES (XRB * NTILE) // 2048 x tasks
// Wimg: hi-plane only now, 4096 ushorts (8KB) per (ntile,kit) tile
#define WIMG_USHORTS ((size_t)NTILE * KIT * 4096)
#define MAXLEV_LDS 128

__device__ __forceinline__ float sigm(float x) { return 1.0f / (1.0f + __expf(-x)); }
__device__ __forceinline__ float tanh_fast(float x) {
    float ax = fabsf(x);
    float e = __expf(2.0f * ax);
    float t = 1.0f - 2.0f / (e + 1.0f);
    return copysignf(t, x);
}
__device__ __forceinline__ uint_t packf(float f) {
    uint_t u = __float_as_uint(f);
    uint_t hi = u & 0xffff0000u;
    float r = f - __uint_as_float(hi);
    return hi | (__float_as_uint(r) >> 16);
}
// round-to-nearest-even fp32 -> bf16 (low 16 of return)
__device__ __forceinline__ uint_t rne16(float f) {
    uint_t u = __float_as_uint(f);
    return (u + 0x7fffu + ((u >> 16) & 1u)) >> 16;
}

// ---------------------------------------------------------------------------
// Prep: weights -> bf16 (hi plane only, RNE) LDS-image layout.
// Image tile (ntile,kit): ushort idx = col*32 + gp*8 + b, gp = gd^(col&3),
//   k = kit*32 + gd*8 + b, j = ntile*128 + col.
// ---------------------------------------------------------------------------
__global__ void __launch_bounds__(256) prep_wimg_kernel(
    const float* __restrict__ Wx_iou_v, const float* __restrict__ Wh_iou_v,
    const float* __restrict__ Wx_f_v,   const float* __restrict__ Wh_f_v,
    const float* __restrict__ Wx_iou_l, const float* __restrict__ Wh_iou_l,
    const float* __restrict__ Wx_f_l,   const float* __restrict__ Wh_f_l,
    ushort_t* __restrict__ Wimg)
{
    __shared__ float T[32][132];   // T[kk][jloc]
    int p = blockIdx.x >> 5, it = blockIdx.x & 31;
    int tid = threadIdx.x;
#pragma unroll
    for (int e = 0; e < 16; ++e) {
        int lin = e * 256 + tid;
        int dloc = lin & 15, kk = (lin >> 4) & 31, q = lin >> 9;
        int d = p * 16 + dloc;
        int qq = q & 3; bool lang = q >= 4;
        int k = it * 32 + kk;
        const float* W; int col, stride;
        if (qq < 3) { col = qq * DIM + d; stride = 3 * DIM;
            W = (k < DIM) ? (lang ? Wx_iou_l : Wx_iou_v) : (lang ? Wh_iou_l : Wh_iou_v); }
        else        { col = d; stride = DIM;
            W = (k < DIM) ? (lang ? Wx_f_l : Wx_f_v) : (lang ? Wh_f_l : Wh_f_v); }
        int kr = (k < DIM) ? k : (k - DIM);
        T[kk][dloc * 8 + q] = W[(size_t)kr * stride + col];
    }
    __syncthreads();
    size_t tilebase = (size_t)blockIdx.x * 4096;
#pragma unroll
    for (int gch = 0; gch < 2; ++gch) {
        int gi = gch * 256 + tid;          // uint4 index 0..511
        int col = gi >> 2, gp = gi & 3;
        int gd = gp ^ (col & 3);
        uint_t wds[4];
#pragma unroll
        for (int i = 0; i < 4; ++i) {
            uint_t v0 = rne16(T[gd * 8 + 2 * i][col]);
            uint_t v1 = rne16(T[gd * 8 + 2 * i + 1][col]);
            wds[i] = (v1 << 16) | v0;
        }
        *(uint4*)(Wimg + tilebase + (size_t)gi * 8) = make_uint4(wds[0], wds[1], wds[2], wds[3]);
    }
}

__global__ void prep_bias_kernel(
    const float* __restrict__ bx_iou_v, const float* __restrict__ bh_iou_v,
    const float* __restrict__ bx_f_v,   const float* __restrict__ bh_f_v,
    const float* __restrict__ bx_iou_l, const float* __restrict__ bh_iou_l,
    const float* __restrict__ bx_f_l,   const float* __restrict__ bh_f_l,
    float* __restrict__ bias)
{
    int j = blockIdx.x * blockDim.x + threadIdx.x;
    if (j >= NCOLS) return;
    int d = j >> 3, q = j & 7;
    int qq = q & 3;
    bool lang = (q & 4) != 0;
    const float* bx; const float* bh; int col;
    if (qq < 3) { col = qq * DIM + d; bx = lang ? bx_iou_l : bx_iou_v; bh = lang ? bh_iou_l : bh_iou_v; }
    else        { col = d;            bx = lang ? bx_f_l  : bx_f_v;   bh = lang ? bh_f_l  : bh_f_v; }
    bias[j] = bx[col] + bh[col];
}

// ---------------------------------------------------------------------------
// Level computation + counting sort + rowblock tables (verified r4/r5)
// ---------------------------------------------------------------------------
__global__ void __launch_bounds__(1024) levels_sort_kernel(
    const int* __restrict__ parent,
    int* __restrict__ order, int* __restrict__ offsets,
    int* __restrict__ counts, int* __restrict__ cursors,
    int* __restrict__ nlev, int* __restrict__ tilestart,
    int* __restrict__ rbStart, int* __restrict__ nodeHrb)
{
    __shared__ int s_level[N_NODES];
    __shared__ int s_assigned;
    __shared__ int s_maxlev;
    int tid = threadIdx.x;
    int pr[8];
#pragma unroll
    for (int ii = 0; ii < 8; ++ii) {
        int i = tid + ii * 1024;
        pr[ii] = parent[i];
        s_level[i] = -1;
    }
    for (int i = tid; i <= N_NODES; i += 1024) counts[i] = 0;
    if (tid == 0) { s_assigned = 0; s_maxlev = 0; }
    __syncthreads();

    for (int pass = 0; pass <= N_NODES; ++pass) {
        int newly = 0;
#pragma unroll
        for (int ii = 0; ii < 8; ++ii) {
            int i = tid + ii * 1024;
            if (s_level[i] < 0) {
                int p = pr[ii];
                if (p == 0) { s_level[i] = 0; newly++; }
                else { int lp = s_level[p - 1]; if (lp >= 0) { s_level[i] = lp + 1; newly++; } }
            }
        }
        if (newly) atomicAdd(&s_assigned, newly);
        __syncthreads();
        int a = s_assigned;
        if (a >= N_NODES) break;
        __syncthreads();
    }

#pragma unroll
    for (int ii = 0; ii < 8; ++ii) {
        int i = tid + ii * 1024;
        int lv = s_level[i];
        atomicAdd(&counts[lv], 1);
        atomicMax(&s_maxlev, lv);
    }
    __syncthreads();
    if (tid == 0) {
        int nl = s_maxlev + 1;
        nlev[0] = nl;
        int off = 0, toff = 0, rb = 0;
        for (int l = 0; l < nl; ++l) {
            offsets[l] = off; cursors[l] = off;
            tilestart[l] = toff; rbStart[l] = rb;
            int mt = (counts[l] + BM - 1) / BM;
            rb += mt;
            toff += mt * NTILE;
            off += counts[l];
        }
        offsets[nl] = off;
        tilestart[nl] = toff;
        rbStart[nl] = rb;
        nlev[1] = toff;   // total h-tiles
    }
    __syncthreads();
#pragma unroll
    for (int ii = 0; ii < 8; ++ii) {
        int i = tid + ii * 1024;
        int lv = s_level[i];
        int pos = atomicAdd(&cursors[lv], 1);
        order[pos] = i;
        nodeHrb[i] = rbStart[lv] + ((pos - offsets[lv]) >> 7);
    }
}

// ---------------------------------------------------------------------------
// Staging helpers
// ---------------------------------------------------------------------------
__device__ __forceinline__ void writeA_words(int tid, ushort_t* Ab,
                                             const uint_t* hw, const uint_t* lw)
{
    int row = tid >> 1, h16 = tid & 1;
    int gd0 = h16 * 2, gd1 = gd0 + 1, rs = row & 3;
    ushort_t* base = Ab + row * 32;
    *(uint4*)(base + (gd0 ^ rs) * 8)        = make_uint4(hw[0], hw[1], hw[2], hw[3]);
    *(uint4*)(base + (gd1 ^ rs) * 8)        = make_uint4(hw[4], hw[5], hw[6], hw[7]);
    *(uint4*)(base + 4096 + (gd0 ^ rs) * 8) = make_uint4(lw[0], lw[1], lw[2], lw[3]);
    *(uint4*)(base + 4096 + (gd1 ^ rs) * 8) = make_uint4(lw[4], lw[5], lw[6], lw[7]);
}

__device__ __forceinline__ void writeA_lds(int tid, ushort_t* Ab, const float* f)
{
    uint_t hw[8], lw[8];
#pragma unroll
    for (int i = 0; i < 8; ++i) {
        float f0 = f[2 * i], f1 = f[2 * i + 1];
        uint_t u0 = __float_as_uint(f0), u1 = __float_as_uint(f1);
        uint_t h0 = u0 & 0xffff0000u, h1 = u1 & 0xffff0000u;
        float r0 = f0 - __uint_as_float(h0), r1 = f1 - __uint_as_float(h1);
        hw[i] = h1 | (h0 >> 16);
        lw[i] = (__float_as_uint(r1) & 0xffff0000u) | (__float_as_uint(r0) >> 16);
    }
    writeA_words(tid, Ab, hw, lw);
}

// x-side A: contiguous node rows (x tiles are node-major)
__device__ __forceinline__ void loadA_x(int it, int tid, int r0,
    const float* __restrict__ inputs, float* f)
{
    int row = tid >> 1, h16 = tid & 1;
    const float* base = inputs + (size_t)(r0 + row) * DIM + it * 32 + h16 * 16;
#pragma unroll
    for (int q4 = 0; q4 < 4; ++q4) {
        float4 v = *(const float4*)(base + q4 * 4);
        f[q4 * 4 + 0] = v.x; f[q4 * 4 + 1] = v.y; f[q4 * 4 + 2] = v.z; f[q4 * 4 + 3] = v.w;
    }
}

// h-side A from packed hi|lo u32 rows
__device__ __forceinline__ void loadA_hpack(int it, int tid,
    const int* s_node, const int* s_par,
    const uint_t* __restrict__ hPack, uint_t* hw, uint_t* lw)
{
    int row = tid >> 1, h16 = tid & 1;
    int p = (s_node[row] >= 0) ? s_par[row] : 0;
    uint_t u[16];
    if (p > 0) {
        const uint4* base = (const uint4*)(hPack + (size_t)(p - 1) * DIM + (it - 16) * 32 + h16 * 16);
#pragma unroll
        for (int q4 = 0; q4 < 4; ++q4) {
            uint4 v = base[q4];
            u[q4 * 4] = v.x; u[q4 * 4 + 1] = v.y; u[q4 * 4 + 2] = v.z; u[q4 * 4 + 3] = v.w;
        }
    } else {
#pragma unroll
        for (int i = 0; i < 16; ++i) u[i] = 0;
    }
#pragma unroll
    for (int i = 0; i < 8; ++i) {
        hw[i] = (u[2 * i + 1] & 0xffff0000u) | (u[2 * i] >> 16);
        lw[i] = (u[2 * i + 1] << 16) | (u[2 * i] & 0xffffu);
    }
}

__device__ __forceinline__ void loadB_regs(int it, int ntile, int tid,
                                           const ushort_t* __restrict__ Wimg, uint4* br)
{
    const uint4* g = (const uint4*)(Wimg + ((size_t)(ntile * KIT + it)) * 4096);
    br[0] = g[tid];
    br[1] = g[tid + 256];
}

__device__ __forceinline__ void writeB_lds(int tid, ushort_t* Bb, const uint4* br)
{
    uint4* d = (uint4*)Bb;
    d[tid] = br[0];
    d[tid + 256] = br[1];
}

// 2-MFMA split: acc += ah*bh + al*bh   (B hi-plane only)
__device__ __forceinline__ void mfma_phase(const ushort_t* Ab, const ushort_t* Bb,
                                           int wr, int wc, int lane, f32x4 acc[4][4])
{
    int l15 = lane & 15, g = lane >> 4;
    short8 ah[4], al[4];
#pragma unroll
    for (int m = 0; m < 4; ++m) {
        int row = wr * 64 + m * 16 + l15;
        const ushort_t* pa = Ab + row * 32 + ((g ^ (row & 3)) * 8);
        ah[m] = *(const short8*)pa;
        al[m] = *(const short8*)(pa + 4096);
    }
#pragma unroll
    for (int n = 0; n < 4; ++n) {
        int col = wc * 64 + n * 16 + l15;
        const ushort_t* pb = Bb + col * 32 + ((g ^ (col & 3)) * 8);
        short8 bh = *(const short8*)pb;
#pragma unroll
        for (int m = 0; m < 4; ++m) {
            acc[m][n] = __builtin_amdgcn_mfma_f32_16x16x32_bf16(ah[m], bh, acc[m][n], 0, 0, 0);
            acc[m][n] = __builtin_amdgcn_mfma_f32_16x16x32_bf16(al[m], bh, acc[m][n], 0, 0, 0);
        }
    }
}

// ---------------------------------------------------------------------------
// Fence-free dataflow (r5 structure): x-tasks write preAct; h-tasks wait on
// parents' rowblock counters, run K=512 h-GEMM (depth-2 prefetch) + epilogue.
// LDS: A0(16K) A1(16K) B0(8K) B1(8K) = 48KB -> 3 blocks/CU.
// ---------------------------------------------------------------------------
__global__ void __launch_bounds__(256, 3) tree_split3_kernel(
    const float* __restrict__ inputs, const float* __restrict__ type_mask,
    const ushort_t* __restrict__ Wimg, const float* __restrict__ bias,
    const int* __restrict__ order, const int* __restrict__ offsets,
    const int* __restrict__ nlev, const int* __restrict__ parent,
    const int* __restrict__ rbStart, const int* __restrict__ nodeHrb,
    int* __restrict__ rbCnt, int* __restrict__ xFlag,
    float* __restrict__ preAct, uint_t* __restrict__ hPack, uint_t* __restrict__ cPack,
    float* __restrict__ out)
{
    float* cOut = out;
    float* hOut = out + (size_t)N_NODES * DIM;

    __shared__ __align__(16) ushort_t sm16[24576];   // 48KB
    __shared__ int s_node[BM];
    __shared__ int s_par[BM];
    __shared__ int s_phrb[BM];
    __shared__ float s_tm[BM][2];
    __shared__ int s_rbs[MAXLEV_LDS];
    __shared__ int s_off[MAXLEV_LDS];

    int tid = threadIdx.x;
    int lane = tid & 63, w = tid >> 6, wr = w >> 1, wc = w & 1;
    int l15 = lane & 15, g = lane >> 4;
    int nl = nlev[0];
    int total = XTILES + nlev[1];

    int nload = nl + 1; if (nload > MAXLEV_LDS) nload = MAXLEV_LDS;
    for (int i = tid; i < nload; i += 256) { s_rbs[i] = rbStart[i]; s_off[i] = offsets[i]; }
    __syncthreads();

#define ABUF(c) (sm16 + (c) * 8192)
#define BBUF(c) (sm16 + 16384 + (c) * 4096)

    for (int t = blockIdx.x; t < total; t += gridDim.x) {
        if (t < XTILES) {
            // ============ x-task: preAct tile (no dependencies) ============
            int ntile = t & (NTILE - 1);
            int xrb = t >> 5;
            int jc = ntile * BN, r0 = xrb * BM;

            f32x4 acc[4][4];
#pragma unroll
            for (int m = 0; m < 4; ++m)
#pragma unroll
                for (int n = 0; n < 4; ++n) acc[m][n] = (f32x4)(0.f);

            {
                float fA[16]; uint4 br[2];
                loadA_x(0, tid, r0, inputs, fA);
                loadB_regs(0, ntile, tid, Wimg, br);
                writeA_lds(tid, ABUF(0), fA);
                writeB_lds(tid, BBUF(0), br);
            }
            __syncthreads();
            int cur = 0;
            for (int it = 0; it < 16; ++it) {
                float fA[16]; uint4 br[2];
                bool hn = it < 15;
                if (hn) {
                    loadA_x(it + 1, tid, r0, inputs, fA);
                    loadB_regs(it + 1, ntile, tid, Wimg, br);
                }
                __builtin_amdgcn_s_setprio(1);
                mfma_phase(ABUF(cur), BBUF(cur), wr, wc, lane, acc);
                __builtin_amdgcn_s_setprio(0);
                if (hn) {
                    writeA_lds(tid, ABUF(cur ^ 1), fA);
                    writeB_lds(tid, BBUF(cur ^ 1), br);
                }
                __syncthreads();
                cur ^= 1;
            }

            // transpose acc in LDS, then contiguous 8B sc1 stores to preAct
            float* eps = (float*)sm16;
#pragma unroll
            for (int pass = 0; pass < 2; ++pass) {
                if (wc == pass) {
#pragma unroll
                    for (int m = 0; m < 4; ++m)
#pragma unroll
                        for (int n = 0; n < 4; ++n) {
                            int row = wr * 64 + m * 16 + g * 4;
                            int c = n * 16 + l15;
#pragma unroll
                            for (int r = 0; r < 4; ++r) eps[(row + r) * 68 + c] = acc[m][n][r];
                        }
                }
                __syncthreads();
#pragma unroll
                for (int e = 0; e < 4; ++e) {
                    int task = e * 256 + tid;
                    int row = task >> 3, dl = task & 7;
                    const float* ep = &eps[row * 68 + dl * 8];
                    u64_t* dst = (u64_t*)(preAct + (size_t)(r0 + row) * NCOLS + jc + pass * 64 + dl * 8);
#pragma unroll
                    for (int k2 = 0; k2 < 4; ++k2) {
                        u64_t v = ((u64_t)__float_as_uint(ep[2 * k2 + 1]) << 32)
                                | (u64_t)__float_as_uint(ep[2 * k2]);
                        __hip_atomic_store(dst + k2, v, __ATOMIC_RELAXED, __HIP_MEMORY_SCOPE_AGENT);
                    }
                }
                __syncthreads();
            }

            __builtin_amdgcn_s_waitcnt(0);
            __syncthreads();
            if (tid == 0)
                __hip_atomic_store(&xFlag[xrb * NTILE + ntile], 1,
                                   __ATOMIC_RELAXED, __HIP_MEMORY_SCOPE_AGENT);
        } else {
            // ============ h-task: recurrent half ============
            int t2 = t - XTILES;
            int lev = 0;
            while (lev + 1 < nload && s_rbs[lev + 1] * NTILE <= t2) ++lev;
            int lt = t2 - s_rbs[lev] * NTILE;
            int ntile = lt % NTILE;
            int mt = lt / NTILE;
            int start = s_off[lev];
            int cnt = s_off[lev + 1] - start;
            int jc = ntile * BN;
            int r0 = mt * BM;
            int myhrb = s_rbs[lev] + mt;

            if (tid < BM) {
                int r = r0 + tid;
                int node = (r < cnt) ? order[start + r] : -1;
                s_node[tid] = node;
                int p = (node >= 0) ? parent[node] : 0;
                s_par[tid] = p;
                s_phrb[tid] = (node >= 0 && p > 0) ? nodeHrb[p - 1] : -1;
                float t0 = 0.f, t1 = 0.f;
                if (node >= 0) { t0 = type_mask[node * 2]; t1 = type_mask[node * 2 + 1]; }
                s_tm[tid][0] = t0; s_tm[tid][1] = t1;
            }
            __syncthreads();

            f32x4 acc[4][4];
#pragma unroll
            for (int m = 0; m < 4; ++m)
#pragma unroll
                for (int n = 0; n < 4; ++n) acc[m][n] = (f32x4)(0.f);

            if (lev > 0) {
                // wait for parents' rowblocks (flag at coherence point)
                if (tid < BM) {
                    int hrb = s_phrb[tid];
                    if (hrb >= 0) {
                        while (__hip_atomic_load(&rbCnt[hrb], __ATOMIC_RELAXED,
                                                 __HIP_MEMORY_SCOPE_AGENT) < NTILE)
                            __builtin_amdgcn_s_sleep(1);
                    }
                }
                __syncthreads();

                // h-GEMM K=512, depth-2 prefetch (static unroll, rule #20)
                uint_t hws[2][8], lws[2][8]; uint4 brs[2][2];
                loadA_hpack(16, tid, s_node, s_par, hPack, hws[0], lws[0]);
                loadB_regs(16, ntile, tid, Wimg, brs[0]);
                writeA_words(tid, ABUF(0), hws[0], lws[0]);
                writeB_lds(tid, BBUF(0), brs[0]);
                loadA_hpack(17, tid, s_node, s_par, hPack, hws[1], lws[1]);
                loadB_regs(17, ntile, tid, Wimg, brs[1]);
                __syncthreads();
#pragma unroll
                for (int k = 16; k < 32; ++k) {
                    const int cur = (k - 16) & 1, nxt = cur ^ 1;
                    if (k + 2 < 32) {
                        loadA_hpack(k + 2, tid, s_node, s_par, hPack, hws[cur], lws[cur]);
                        loadB_regs(k + 2, ntile, tid, Wimg, brs[cur]);
                    }
                    __builtin_amdgcn_s_setprio(1);
                    mfma_phase(ABUF(cur), BBUF(cur), wr, wc, lane, acc);
                    __builtin_amdgcn_s_setprio(0);
                    if (k + 1 < 32) {
                        writeA_words(tid, ABUF(nxt), hws[nxt], lws[nxt]);
                        writeB_lds(tid, BBUF(nxt), brs[nxt]);
                    }
                    __syncthreads();
                }
            }

            // wait for own preAct column tile
            if (tid < BM) {
                int node = s_node[tid];
                if (node >= 0) {
                    int xi = (node >> 7) * NTILE + ntile;
                    while (__hip_atomic_load(&xFlag[xi], __ATOMIC_RELAXED,
                                             __HIP_MEMORY_SCOPE_AGENT) == 0)
                        __builtin_amdgcn_s_sleep(1);
                }
            }
            __syncthreads();

            // epilogue: acc transpose + preAct + bias + LSTM cell
            float* eps = (float*)sm16;
            int cntloc = cnt - r0; if (cntloc > BM) cntloc = BM;
#pragma unroll
            for (int pass = 0; pass < 2; ++pass) {
                if (wc == pass) {
#pragma unroll
                    for (int m = 0; m < 4; ++m)
#pragma unroll
                        for (int n = 0; n < 4; ++n) {
                            int row = wr * 64 + m * 16 + g * 4;
                            int c = n * 16 + l15;
#pragma unroll
                            for (int r = 0; r < 4; ++r) eps[(row + r) * 68 + c] = acc[m][n][r];
                        }
                }
                __syncthreads();
#pragma unroll
                for (int e = 0; e < 4; ++e) {
                    int task = e * 256 + tid;
                    int row = task >> 3, dl = task & 7;
                    if (row < cntloc) {
                        int node = s_node[row]; int p = s_par[row];
                        const float* ep = &eps[row * 68 + dl * 8];
                        float4 v0 = *(const float4*)ep;
                        float4 v1 = *(const float4*)(ep + 4);
                        int jb = jc + pass * 64 + dl * 8;
                        const float* pa = preAct + (size_t)node * NCOLS + jb;
                        float4 p0 = *(const float4*)pa;
                        float4 p1 = *(const float4*)(pa + 4);
                        float4 b0 = *(const float4*)(bias + jb);
                        float4 b1 = *(const float4*)(bias + jb + 4);
                        int d = jb >> 3;
                        float cp = 0.f;
                        if (p > 0) {
                            uint_t wrd = cPack[(size_t)(p - 1) * DIM + d];
                            cp = __uint_as_float(wrd & 0xffff0000u) + __uint_as_float(wrd << 16);
                        }
                        float cv = sigm(v0.x + p0.x + b0.x) * tanh_fast(v0.z + p0.z + b0.z)
                                 + sigm(v0.w + p0.w + b0.w) * cp;
                        float hv = sigm(v0.y + p0.y + b0.y) * tanh_fast(cv);
                        float cl = sigm(v1.x + p1.x + b1.x) * tanh_fast(v1.z + p1.z + b1.z)
                                 + sigm(v1.w + p1.w + b1.w) * cp;
                        float hl = sigm(v1.y + p1.y + b1.y) * tanh_fast(cl);
                        float tm0 = s_tm[row][0], tm1 = s_tm[row][1];
                        float cn = tm0 * cl + tm1 * cv;
                        float hn2 = tm0 * hl + tm1 * hv;
                        size_t oi = (size_t)node * DIM + d;
                        cOut[oi] = cn;
                        hOut[oi] = hn2;
                        __hip_atomic_store(&cPack[oi], packf(cn),
                                           __ATOMIC_RELAXED, __HIP_MEMORY_SCOPE_AGENT);
                        __hip_atomic_store(&hPack[oi], packf(hn2),
                                           __ATOMIC_RELAXED, __HIP_MEMORY_SCOPE_AGENT);
                    }
                }
                __syncthreads();
            }

            __builtin_amdgcn_s_waitcnt(0);   // drain this wave's sc1 stores
            __syncthreads();
            if (tid == 0)
                __hip_atomic_fetch_add(&rbCnt[myhrb], 1, __ATOMIC_RELAXED,
                                       __HIP_MEMORY_SCOPE_AGENT);
        }
    }
#undef ABUF
#undef BBUF
}

// ---------------------------------------------------------------------------
extern "C" void kernel_launch(void* const* d_in, const int* in_sizes, int n_in,
                              void* d_out, int out_size, void* d_ws, size_t ws_size,
                              hipStream_t stream) {
    const float* inputs      = (const float*)d_in[0];
    const float* type_mask   = (const float*)d_in[1];
    const int*   parent      = (const int*)d_in[2];
    const float* W_ioux_vis  = (const float*)d_in[3];
    const float* b_ioux_vis  = (const float*)d_in[4];
    const float* W_iouh_vis  = (const float*)d_in[5];
    const float* b_iouh_vis  = (const float*)d_in[6];
    const float* W_fx_vis    = (const float*)d_in[7];
    const float* b_fx_vis    = (const float*)d_in[8];
    const float* W_fh_vis    = (const float*)d_in[9];
    const float* b_fh_vis    = (const float*)d_in[10];
    const float* W_ioux_lang = (const float*)d_in[11];
    const float* b_ioux_lang = (const float*)d_in[12];
    const float* W_iouh_lang = (const float*)d_in[13];
    const float* b_iouh_lang = (const float*)d_in[14];
    const float* W_fx_lang   = (const float*)d_in[15];
    const float* b_fx_lang   = (const float*)d_in[16];
    const float* W_fh_lang   = (const float*)d_in[17];
    const float* b_fh_lang   = (const float*)d_in[18];

    ushort_t* Wimg = (ushort_t*)d_ws;                      // 8 MB
    float* bias    = (float*)(Wimg + WIMG_USHORTS);
    int* order     = (int*)(bias + NCOLS);
    int* offsets   = order + N_NODES;
    int* counts    = offsets + (N_NODES + 2);
    int* cursors   = counts + (N_NODES + 2);
    int* nlev      = cursors + (N_NODES + 2);
    int* tilestart = nlev + 8;
    int* rbStart   = tilestart + (N_NODES + 2);
    int* nodeHrb   = rbStart + (N_NODES + 2);
    int* rbCnt     = nodeHrb + N_NODES;
    int* xFlag     = rbCnt + 4096;
    size_t off2 = (size_t)((char*)(xFlag + XTILES) - (char*)d_ws);
    off2 = (off2 + 255) & ~(size_t)255;
    uint_t* hPack = (uint_t*)((char*)d_ws + off2);                       // 16 MB
    uint_t* cPack = hPack + (size_t)N_NODES * DIM;                       // 16 MB
    float* preAct = (float*)(cPack + (size_t)N_NODES * DIM);             // 128 MB

    float* out = (float*)d_out;

    hipMemsetAsync((void*)rbCnt, 0, (4096 + XTILES) * sizeof(int), stream);

    hipLaunchKernelGGL(prep_wimg_kernel, dim3(NTILE * KIT), dim3(256), 0, stream,
                       W_ioux_vis, W_iouh_vis, W_fx_vis, W_fh_vis,
                       W_ioux_lang, W_iouh_lang, W_fx_lang, W_fh_lang, Wimg);
    hipLaunchKernelGGL(prep_bias_kernel, dim3(NCOLS / 256), dim3(256), 0, stream,
                       b_ioux_vis, b_iouh_vis, b_fx_vis, b_fh_vis,
                       b_ioux_lang, b_iouh_lang, b_fx_lang, b_fh_lang, bias);
    hipLaunchKernelGGL(levels_sort_kernel, dim3(1), dim3(1024), 0, stream,
                       parent, order, offsets, counts, cursors, nlev, tilestart,
                       rbStart, nodeHrb);

    int occ = 0;
    if (hipOccupancyMaxActiveBlocksPerMultiprocessor(&occ, (const void*)tree_split3_kernel, 256, 0) != hipSuccess || occ < 1)
        occ = 1;
    int bpc = occ < 3 ? occ : 3;
    dim3 grid(256 * bpc);

    void* args[] = { (void*)&inputs, (void*)&type_mask, (void*)&Wimg, (void*)&bias,
                     (void*)&order, (void*)&offsets, (void*)&nlev, (void*)&parent,
                     (void*)&rbStart, (void*)&nodeHrb, (void*)&rbCnt, (void*)&xFlag,
                     (void*)&preAct, (void*)&hPack, (void*)&cPack, (void*)&out };
    hipLaunchCooperativeKernel((const void*)tree_split3_kernel, grid, dim3(256), args, 0, stream);
}

// Round 8
// 1092.673 us; speedup vs baseline: 1.2052x; 1.0149x over previous
//
#include <hip/hip_runtime.h>
#include <math.h>

typedef unsigned short ushort_t;
typedef unsigned int uint_t;
typedef unsigned long long u64_t;
typedef __attribute__((ext_vector_type(8))) short short8;
typedef __attribute__((ext_vector_type(4))) float f32x4;

#define N_NODES 8192
#define DIM 512
#define KTOT 1024
#define NCOLS 4096
#define BM 128
#define BN 128
#define NTILE (NCOLS / BN)   // 32 column tiles
#define KIT (KTOT / 32)      // 32 k iterations (BK=32)
#define XRB (N_NODES / BM)   // 64 node rowblocks
#define XTILES (XRB * NTILE) // 2048 x tasks
// Wimg: hi-plane bf16, direct-fragment layout: tile(ntile,it) 128 cols x 32 k
// ushort idx = col*32 + g*8 + b  (NO swizzle: read straight from global)
#define WIMG_USHORTS ((size_t)NTILE * KIT * 4096)
#define MAXLEV_LDS 128

__device__ __forceinline__ float sigm(float x) { return 1.0f / (1.0f + __expf(-x)); }
__device__ __forceinline__ float tanh_fast(float x) {
    float ax = fabsf(x);
    float e = __expf(2.0f * ax);
    float t = 1.0f - 2.0f / (e + 1.0f);
    return copysignf(t, x);
}
__device__ __forceinline__ uint_t packf(float f) {
    uint_t u = __float_as_uint(f);
    uint_t hi = u & 0xffff0000u;
    float r = f - __uint_as_float(hi);
    return hi | (__float_as_uint(r) >> 16);
}
__device__ __forceinline__ uint_t rne16(float f) {
    uint_t u = __float_as_uint(f);
    return (u + 0x7fffu + ((u >> 16) & 1u)) >> 16;
}

// split 8 packed (hi|lo) u32 -> hi-frag / lo-frag short8
__device__ __forceinline__ void fragAB_u32(const uint4 w0, const uint4 w1,
                                           short8& hi8, short8& lo8) {
    union { uint_t w[4]; short8 s; } H, L;
    uint_t u[8] = { w0.x, w0.y, w0.z, w0.w, w1.x, w1.y, w1.z, w1.w };
#pragma unroll
    for (int j = 0; j < 4; ++j) {
        H.w[j] = (u[2 * j + 1] & 0xffff0000u) | (u[2 * j] >> 16);
        L.w[j] = (u[2 * j + 1] << 16) | (u[2 * j] & 0xffffu);
    }
    hi8 = H.s; lo8 = L.s;
}

// split 8 fp32 -> hi-frag (trunc) / lo-frag (residual) short8
__device__ __forceinline__ void fragA_f32(const float4 f0, const float4 f1,
                                          short8& hi8, short8& lo8) {
    union { uint_t w[4]; short8 s; } H, L;
    float f[8] = { f0.x, f0.y, f0.z, f0.w, f1.x, f1.y, f1.z, f1.w };
#pragma unroll
    for (int j = 0; j < 4; ++j) {
        float a = f[2 * j], b = f[2 * j + 1];
        uint_t h0 = __float_as_uint(a) & 0xffff0000u;
        uint_t h1 = __float_as_uint(b) & 0xffff0000u;
        float r0 = a - __uint_as_float(h0);
        float r1 = b - __uint_as_float(h1);
        H.w[j] = h1 | (h0 >> 16);
        L.w[j] = (__float_as_uint(r1) & 0xffff0000u) | (__float_as_uint(r0) >> 16);
    }
    hi8 = H.s; lo8 = L.s;
}

// ---------------------------------------------------------------------------
// Prep: weights -> bf16 (hi plane, RNE), direct-fragment image (no swizzle)
// ---------------------------------------------------------------------------
__global__ void __launch_bounds__(256) prep_wimg_kernel(
    const float* __restrict__ Wx_iou_v, const float* __restrict__ Wh_iou_v,
    const float* __restrict__ Wx_f_v,   const float* __restrict__ Wh_f_v,
    const float* __restrict__ Wx_iou_l, const float* __restrict__ Wh_iou_l,
    const float* __restrict__ Wx_f_l,   const float* __restrict__ Wh_f_l,
    ushort_t* __restrict__ Wimg)
{
    __shared__ float T[32][132];   // T[kk][jloc]
    int p = blockIdx.x >> 5, it = blockIdx.x & 31;
    int tid = threadIdx.x;
#pragma unroll
    for (int e = 0; e < 16; ++e) {
        int lin = e * 256 + tid;
        int dloc = lin & 15, kk = (lin >> 4) & 31, q = lin >> 9;
        int d = p * 16 + dloc;
        int qq = q & 3; bool lang = q >= 4;
        int k = it * 32 + kk;
        const float* W; int col, stride;
        if (qq < 3) { col = qq * DIM + d; stride = 3 * DIM;
            W = (k < DIM) ? (lang ? Wx_iou_l : Wx_iou_v) : (lang ? Wh_iou_l : Wh_iou_v); }
        else        { col = d; stride = DIM;
            W = (k < DIM) ? (lang ? Wx_f_l : Wx_f_v) : (lang ? Wh_f_l : Wh_f_v); }
        int kr = (k < DIM) ? k : (k - DIM);
        T[kk][dloc * 8 + q] = W[(size_t)kr * stride + col];
    }
    __syncthreads();
    size_t tilebase = (size_t)blockIdx.x * 4096;
#pragma unroll
    for (int gch = 0; gch < 2; ++gch) {
        int gi = gch * 256 + tid;          // uint4 index 0..511
        int col = gi >> 2, gd = gi & 3;    // direct: physical granule == logical
        uint_t wds[4];
#pragma unroll
        for (int i = 0; i < 4; ++i) {
            uint_t v0 = rne16(T[gd * 8 + 2 * i][col]);
            uint_t v1 = rne16(T[gd * 8 + 2 * i + 1][col]);
            wds[i] = (v1 << 16) | v0;
        }
        *(uint4*)(Wimg + tilebase + (size_t)gi * 8) = make_uint4(wds[0], wds[1], wds[2], wds[3]);
    }
}

__global__ void prep_bias_kernel(
    const float* __restrict__ bx_iou_v, const float* __restrict__ bh_iou_v,
    const float* __restrict__ bx_f_v,   const float* __restrict__ bh_f_v,
    const float* __restrict__ bx_iou_l, const float* __restrict__ bh_iou_l,
    const float* __restrict__ bx_f_l,   const float* __restrict__ bh_f_l,
    float* __restrict__ bias)
{
    int j = blockIdx.x * blockDim.x + threadIdx.x;
    if (j >= NCOLS) return;
    int d = j >> 3, q = j & 7;
    int qq = q & 3;
    bool lang = (q & 4) != 0;
    const float* bx; const float* bh; int col;
    if (qq < 3) { col = qq * DIM + d; bx = lang ? bx_iou_l : bx_iou_v; bh = lang ? bh_iou_l : bh_iou_v; }
    else        { col = d;            bx = lang ? bx_f_l  : bx_f_v;   bh = lang ? bh_f_l  : bh_f_v; }
    bias[j] = bx[col] + bh[col];
}

// ---------------------------------------------------------------------------
// Level computation + counting sort + rowblock tables (verified r4-r7)
// ---------------------------------------------------------------------------
__global__ void __launch_bounds__(1024) levels_sort_kernel(
    const int* __restrict__ parent,
    int* __restrict__ order, int* __restrict__ offsets,
    int* __restrict__ counts, int* __restrict__ cursors,
    int* __restrict__ nlev, int* __restrict__ tilestart,
    int* __restrict__ rbStart, int* __restrict__ nodeHrb)
{
    __shared__ int s_level[N_NODES];
    __shared__ int s_assigned;
    __shared__ int s_maxlev;
    int tid = threadIdx.x;
    int pr[8];
#pragma unroll
    for (int ii = 0; ii < 8; ++ii) {
        int i = tid + ii * 1024;
        pr[ii] = parent[i];
        s_level[i] = -1;
    }
    for (int i = tid; i <= N_NODES; i += 1024) counts[i] = 0;
    if (tid == 0) { s_assigned = 0; s_maxlev = 0; }
    __syncthreads();

    for (int pass = 0; pass <= N_NODES; ++pass) {
        int newly = 0;
#pragma unroll
        for (int ii = 0; ii < 8; ++ii) {
            int i = tid + ii * 1024;
            if (s_level[i] < 0) {
                int p = pr[ii];
                if (p == 0) { s_level[i] = 0; newly++; }
                else { int lp = s_level[p - 1]; if (lp >= 0) { s_level[i] = lp + 1; newly++; } }
            }
        }
        if (newly) atomicAdd(&s_assigned, newly);
        __syncthreads();
        int a = s_assigned;
        if (a >= N_NODES) break;
        __syncthreads();
    }

#pragma unroll
    for (int ii = 0; ii < 8; ++ii) {
        int i = tid + ii * 1024;
        int lv = s_level[i];
        atomicAdd(&counts[lv], 1);
        atomicMax(&s_maxlev, lv);
    }
    __syncthreads();
    if (tid == 0) {
        int nl = s_maxlev + 1;
        nlev[0] = nl;
        int off = 0, toff = 0, rb = 0;
        for (int l = 0; l < nl; ++l) {
            offsets[l] = off; cursors[l] = off;
            tilestart[l] = toff; rbStart[l] = rb;
            int mt = (counts[l] + BM - 1) / BM;
            rb += mt;
            toff += mt * NTILE;
            off += counts[l];
        }
        offsets[nl] = off;
        tilestart[nl] = toff;
        rbStart[nl] = rb;
        nlev[1] = toff;   // total h-tiles
    }
    __syncthreads();
#pragma unroll
    for (int ii = 0; ii < 8; ++ii) {
        int i = tid + ii * 1024;
        int lv = s_level[i];
        int pos = atomicAdd(&cursors[lv], 1);
        order[pos] = i;
        nodeHrb[i] = rbStart[lv] + ((pos - offsets[lv]) >> 7);
    }
}

// ---------------------------------------------------------------------------
// Worker: LDS-free register GEMM (direct per-lane fragment loads),
// fence-free dataflow, LDS used only for the epilogue transpose.
// ---------------------------------------------------------------------------
__global__ void __launch_bounds__(256, 2) tree_reg_kernel(
    const float* __restrict__ inputs, const float* __restrict__ type_mask,
    const ushort_t* __restrict__ Wimg, const float* __restrict__ bias,
    const int* __restrict__ order, const int* __restrict__ offsets,
    const int* __restrict__ nlev, const int* __restrict__ parent,
    const int* __restrict__ rbStart, const int* __restrict__ nodeHrb,
    int* __restrict__ rbCnt, int* __restrict__ xFlag,
    float* __restrict__ preAct, uint_t* __restrict__ hPack, uint_t* __restrict__ cPack,
    float* __restrict__ out)
{
    float* cOut = out;
    float* hOut = out + (size_t)N_NODES * DIM;

    __shared__ float eps[BM * 68];       // 34.8 KB epilogue transpose
    __shared__ int s_node[BM];
    __shared__ int s_par[BM];
    __shared__ int s_phrb[BM];
    __shared__ float s_tm[BM][2];
    __shared__ int s_rbs[MAXLEV_LDS];
    __shared__ int s_off[MAXLEV_LDS];

    int tid = threadIdx.x;
    int lane = tid & 63, w = tid >> 6, wr = w >> 1, wc = w & 1;
    int l15 = lane & 15, g = lane >> 4;
    int nl = nlev[0];
    int total = XTILES + nlev[1];

    int nload = nl + 1; if (nload > MAXLEV_LDS) nload = MAXLEV_LDS;
    for (int i = tid; i < nload; i += 256) { s_rbs[i] = rbStart[i]; s_off[i] = offsets[i]; }
    __syncthreads();

    // B fragment base for this lane (ushort units); tile stride 4096, n stride 512
    const ushort_t* bLane = Wimg + (size_t)(wc * 64 + l15) * 32 + (size_t)g * 8;

// ---- macros: static-index register pipeline (rule #20 safe) ----
#define LDB(RB, tilebase, itt) { \
    _Pragma("unroll") for (int n_ = 0; n_ < 4; ++n_) \
        RB[n_] = *(const uint4*)(bLane + (size_t)(tilebase + (itt)) * 4096 + n_ * 512); }

#define LDA_H(RA, itrel) { \
    _Pragma("unroll") for (int m_ = 0; m_ < 4; ++m_) { \
        const uint4* p_ = (const uint4*)(aBaseH[m_] + (itrel) * 32 + g * 8); \
        RA[m_][0] = p_[0]; RA[m_][1] = p_[1]; } }

#define LDA_X(RA, itt) { \
    _Pragma("unroll") for (int m_ = 0; m_ < 4; ++m_) { \
        const float4* p_ = (const float4*)(aBaseX[m_] + (itt) * 32 + g * 8); \
        RA[m_][0] = p_[0]; RA[m_][1] = p_[1]; } }

#define COMP_H(RA, RB) { \
    short8 bh_[4]; \
    _Pragma("unroll") for (int n_ = 0; n_ < 4; ++n_) { \
        union { uint4 u; short8 s; } c_; c_.u = RB[n_]; bh_[n_] = c_.s; } \
    _Pragma("unroll") for (int m_ = 0; m_ < 4; ++m_) { \
        short8 ah_, al_; fragAB_u32(RA[m_][0], RA[m_][1], ah_, al_); \
        _Pragma("unroll") for (int n_ = 0; n_ < 4; ++n_) { \
            acc[m_][n_] = __builtin_amdgcn_mfma_f32_16x16x32_bf16(ah_, bh_[n_], acc[m_][n_], 0, 0, 0); \
            acc[m_][n_] = __builtin_amdgcn_mfma_f32_16x16x32_bf16(al_, bh_[n_], acc[m_][n_], 0, 0, 0); } } }

#define COMP_X(RA, RB) { \
    short8 bh_[4]; \
    _Pragma("unroll") for (int n_ = 0; n_ < 4; ++n_) { \
        union { uint4 u; short8 s; } c_; c_.u = RB[n_]; bh_[n_] = c_.s; } \
    _Pragma("unroll") for (int m_ = 0; m_ < 4; ++m_) { \
        short8 ah_, al_; fragA_f32(RA[m_][0], RA[m_][1], ah_, al_); \
        _Pragma("unroll") for (int n_ = 0; n_ < 4; ++n_) { \
            acc[m_][n_] = __builtin_amdgcn_mfma_f32_16x16x32_bf16(ah_, bh_[n_], acc[m_][n_], 0, 0, 0); \
            acc[m_][n_] = __builtin_amdgcn_mfma_f32_16x16x32_bf16(al_, bh_[n_], acc[m_][n_], 0, 0, 0); } } }

    for (int t = blockIdx.x; t < total; t += gridDim.x) {
        if (t < XTILES) {
            // ============ x-task: preAct tile (no dependencies) ============
            int ntile = t & (NTILE - 1);
            int xrb = t >> 5;
            int jc = ntile * BN, r0 = xrb * BM;
            int tb = ntile * KIT;   // Wimg tile base index (x uses it 0..15)

            const float* aBaseX[4];
#pragma unroll
            for (int m = 0; m < 4; ++m)
                aBaseX[m] = inputs + (size_t)(r0 + wr * 64 + m * 16 + l15) * DIM;

            f32x4 acc[4][4];
#pragma unroll
            for (int m = 0; m < 4; ++m)
#pragma unroll
                for (int n = 0; n < 4; ++n) acc[m][n] = (f32x4)(0.f);

            float4 xa0[4][2], xa1[4][2]; uint4 xb0[4], xb1[4];
            LDA_X(xa0, 0); LDB(xb0, tb, 0);
#pragma unroll
            for (int ii = 0; ii < 8; ++ii) {
                int e = 2 * ii, o = e + 1;
                LDA_X(xa1, o); LDB(xb1, tb, o);
                COMP_X(xa0, xb0);
                if (e + 2 < 16) { LDA_X(xa0, e + 2); LDB(xb0, tb, e + 2); }
                COMP_X(xa1, xb1);
            }

            // transpose acc in LDS, contiguous 8B sc1 stores to preAct
            __syncthreads();
#pragma unroll
            for (int pass = 0; pass < 2; ++pass) {
                if (wc == pass) {
#pragma unroll
                    for (int m = 0; m < 4; ++m)
#pragma unroll
                        for (int n = 0; n < 4; ++n) {
                            int row = wr * 64 + m * 16 + g * 4;
                            int c = n * 16 + l15;
#pragma unroll
                            for (int r = 0; r < 4; ++r) eps[(row + r) * 68 + c] = acc[m][n][r];
                        }
                }
                __syncthreads();
#pragma unroll
                for (int e = 0; e < 4; ++e) {
                    int task = e * 256 + tid;
                    int row = task >> 3, dl = task & 7;
                    const float* ep = &eps[row * 68 + dl * 8];
                    u64_t* dst = (u64_t*)(preAct + (size_t)(r0 + row) * NCOLS + jc + pass * 64 + dl * 8);
#pragma unroll
                    for (int k2 = 0; k2 < 4; ++k2) {
                        u64_t v = ((u64_t)__float_as_uint(ep[2 * k2 + 1]) << 32)
                                | (u64_t)__float_as_uint(ep[2 * k2]);
                        __hip_atomic_store(dst + k2, v, __ATOMIC_RELAXED, __HIP_MEMORY_SCOPE_AGENT);
                    }
                }
                __syncthreads();
            }

            __builtin_amdgcn_s_waitcnt(0);
            __syncthreads();
            if (tid == 0)
                __hip_atomic_store(&xFlag[xrb * NTILE + ntile], 1,
                                   __ATOMIC_RELAXED, __HIP_MEMORY_SCOPE_AGENT);
        } else {
            // ============ h-task: recurrent half ============
            int t2 = t - XTILES;
            int lev = 0;
            while (lev + 1 < nload && s_rbs[lev + 1] * NTILE <= t2) ++lev;
            int lt = t2 - s_rbs[lev] * NTILE;
            int ntile = lt % NTILE;
            int mt = lt / NTILE;
            int start = s_off[lev];
            int cnt = s_off[lev + 1] - start;
            int jc = ntile * BN;
            int r0 = mt * BM;
            int myhrb = s_rbs[lev] + mt;
            int tb = ntile * KIT + 16;   // h uses Wimg it 16..31

            if (tid < BM) {
                int r = r0 + tid;
                int node = (r < cnt) ? order[start + r] : -1;
                s_node[tid] = node;
                int p = (node >= 0) ? parent[node] : 0;
                s_par[tid] = p;
                s_phrb[tid] = (node >= 0 && p > 0) ? nodeHrb[p - 1] : -1;
                float t0 = 0.f, t1 = 0.f;
                if (node >= 0) { t0 = type_mask[node * 2]; t1 = type_mask[node * 2 + 1]; }
                s_tm[tid][0] = t0; s_tm[tid][1] = t1;
            }
            __syncthreads();

            f32x4 acc[4][4];
#pragma unroll
            for (int m = 0; m < 4; ++m)
#pragma unroll
                for (int n = 0; n < 4; ++n) acc[m][n] = (f32x4)(0.f);

            if (lev > 0) {
                // wait for parents' rowblocks
                if (tid < BM) {
                    int hrb = s_phrb[tid];
                    if (hrb >= 0) {
                        while (__hip_atomic_load(&rbCnt[hrb], __ATOMIC_RELAXED,
                                                 __HIP_MEMORY_SCOPE_AGENT) < NTILE)
                            __builtin_amdgcn_s_sleep(1);
                    }
                }
                __syncthreads();

                // per-lane parent row base pointers (padding rows -> row 0, discarded)
                const uint_t* aBaseH[4];
#pragma unroll
                for (int m = 0; m < 4; ++m) {
                    int p = s_par[wr * 64 + m * 16 + l15];
                    aBaseH[m] = hPack + (size_t)((p > 0) ? (p - 1) : 0) * DIM;
                }

                uint4 ha0[4][2], ha1[4][2]; uint4 hb0[4], hb1[4];
                LDA_H(ha0, 0); LDB(hb0, tb, 0);
#pragma unroll
                for (int ii = 0; ii < 8; ++ii) {
                    int e = 2 * ii, o = e + 1;
                    LDA_H(ha1, o); LDB(hb1, tb, o);
                    COMP_H(ha0, hb0);
                    if (e + 2 < 16) { LDA_H(ha0, e + 2); LDB(hb0, tb, e + 2); }
                    COMP_H(ha1, hb1);
                }
            }

            // wait for own preAct column tile
            if (tid < BM) {
                int node = s_node[tid];
                if (node >= 0) {
                    int xi = (node >> 7) * NTILE + ntile;
                    while (__hip_atomic_load(&xFlag[xi], __ATOMIC_RELAXED,
                                             __HIP_MEMORY_SCOPE_AGENT) == 0)
                        __builtin_amdgcn_s_sleep(1);
                }
            }
            __syncthreads();

            // epilogue: acc transpose + preAct + bias + LSTM cell
            int cntloc = cnt - r0; if (cntloc > BM) cntloc = BM;
#pragma unroll
            for (int pass = 0; pass < 2; ++pass) {
                if (wc == pass) {
#pragma unroll
                    for (int m = 0; m < 4; ++m)
#pragma unroll
                        for (int n = 0; n < 4; ++n) {
                            int row = wr * 64 + m * 16 + g * 4;
                            int c = n * 16 + l15;
#pragma unroll
                            for (int r = 0; r < 4; ++r) eps[(row + r) * 68 + c] = acc[m][n][r];
                        }
                }
                __syncthreads();
#pragma unroll
                for (int e = 0; e < 4; ++e) {
                    int task = e * 256 + tid;
                    int row = task >> 3, dl = task & 7;
                    if (row < cntloc) {
                        int node = s_node[row]; int p = s_par[row];
                        const float* ep = &eps[row * 68 + dl * 8];
                        float4 v0 = *(const float4*)ep;
                        float4 v1 = *(const float4*)(ep + 4);
                        int jb = jc + pass * 64 + dl * 8;
                        const float* pa = preAct + (size_t)node * NCOLS + jb;
                        float4 p0 = *(const float4*)pa;
                        float4 p1 = *(const float4*)(pa + 4);
                        float4 b0 = *(const float4*)(bias + jb);
                        float4 b1 = *(const float4*)(bias + jb + 4);
                        int d = jb >> 3;
                        float cp = 0.f;
                        if (p > 0) {
                            uint_t wrd = cPack[(size_t)(p - 1) * DIM + d];
                            cp = __uint_as_float(wrd & 0xffff0000u) + __uint_as_float(wrd << 16);
                        }
                        float cv = sigm(v0.x + p0.x + b0.x) * tanh_fast(v0.z + p0.z + b0.z)
                                 + sigm(v0.w + p0.w + b0.w) * cp;
                        float hv = sigm(v0.y + p0.y + b0.y) * tanh_fast(cv);
                        float cl = sigm(v1.x + p1.x + b1.x) * tanh_fast(v1.z + p1.z + b1.z)
                                 + sigm(v1.w + p1.w + b1.w) * cp;
                        float hl = sigm(v1.y + p1.y + b1.y) * tanh_fast(cl);
                        float tm0 = s_tm[row][0], tm1 = s_tm[row][1];
                        float cn = tm0 * cl + tm1 * cv;
                        float hn2 = tm0 * hl + tm1 * hv;
                        size_t oi = (size_t)node * DIM + d;
                        cOut[oi] = cn;
                        hOut[oi] = hn2;
                        __hip_atomic_store(&cPack[oi], packf(cn),
                                           __ATOMIC_RELAXED, __HIP_MEMORY_SCOPE_AGENT);
                        __hip_atomic_store(&hPack[oi], packf(hn2),
                                           __ATOMIC_RELAXED, __HIP_MEMORY_SCOPE_AGENT);
                    }
                }
                __syncthreads();
            }

            __builtin_amdgcn_s_waitcnt(0);
            __syncthreads();
            if (tid == 0)
                __hip_atomic_fetch_add(&rbCnt[myhrb], 1, __ATOMIC_RELAXED,
                                       __HIP_MEMORY_SCOPE_AGENT);
        }
    }
#undef LDB
#undef LDA_H
#undef LDA_X
#undef COMP_H
#undef COMP_X
}

// ---------------------------------------------------------------------------
extern "C" void kernel_launch(void* const* d_in, const int* in_sizes, int n_in,
                              void* d_out, int out_size, void* d_ws, size_t ws_size,
                              hipStream_t stream) {
    const float* inputs      = (const float*)d_in[0];
    const float* type_mask   = (const float*)d_in[1];
    const int*   parent      = (const int*)d_in[2];
    const float* W_ioux_vis  = (const float*)d_in[3];
    const float* b_ioux_vis  = (const float*)d_in[4];
    const float* W_iouh_vis  = (const float*)d_in[5];
    const float* b_iouh_vis  = (const float*)d_in[6];
    const float* W_fx_vis    = (const float*)d_in[7];
    const float* b_fx_vis    = (const float*)d_in[8];
    const float* W_fh_vis    = (const float*)d_in[9];
    const float* b_fh_vis    = (const float*)d_in[10];
    const float* W_ioux_lang = (const float*)d_in[11];
    const float* b_ioux_lang = (const float*)d_in[12];
    const float* W_iouh_lang = (const float*)d_in[13];
    const float* b_iouh_lang = (const float*)d_in[14];
    const float* W_fx_lang   = (const float*)d_in[15];
    const float* b_fx_lang   = (const float*)d_in[16];
    const float* W_fh_lang   = (const float*)d_in[17];
    const float* b_fh_lang   = (const float*)d_in[18];

    ushort_t* Wimg = (ushort_t*)d_ws;                      // 8 MB
    float* bias    = (float*)(Wimg + WIMG_USHORTS);
    int* order     = (int*)(bias + NCOLS);
    int* offsets   = order + N_NODES;
    int* counts    = offsets + (N_NODES + 2);
    int* cursors   = counts + (N_NODES + 2);
    int* nlev      = cursors + (N_NODES + 2);
    int* tilestart = nlev + 8;
    int* rbStart   = tilestart + (N_NODES + 2);
    int* nodeHrb   = rbStart + (N_NODES + 2);
    int* rbCnt     = nodeHrb + N_NODES;
    int* xFlag     = rbCnt + 4096;
    size_t off2 = (size_t)((char*)(xFlag + XTILES) - (char*)d_ws);
    off2 = (off2 + 255) & ~(size_t)255;
    uint_t* hPack = (uint_t*)((char*)d_ws + off2);                       // 16 MB
    uint_t* cPack = hPack + (size_t)N_NODES * DIM;                       // 16 MB
    float* preAct = (float*)(cPack + (size_t)N_NODES * DIM);             // 128 MB

    float* out = (float*)d_out;

    hipMemsetAsync((void*)rbCnt, 0, (4096 + XTILES) * sizeof(int), stream);

    hipLaunchKernelGGL(prep_wimg_kernel, dim3(NTILE * KIT), dim3(256), 0, stream,
                       W_ioux_vis, W_iouh_vis, W_fx_vis, W_fh_vis,
                       W_ioux_lang, W_iouh_lang, W_fx_lang, W_fh_lang, Wimg);
    hipLaunchKernelGGL(prep_bias_kernel, dim3(NCOLS / 256), dim3(256), 0, stream,
                       b_ioux_vis, b_iouh_vis, b_fx_vis, b_fh_vis,
                       b_ioux_lang, b_iouh_lang, b_fx_lang, b_fh_lang, bias);
    hipLaunchKernelGGL(levels_sort_kernel, dim3(1), dim3(1024), 0, stream,
                       parent, order, offsets, counts, cursors, nlev, tilestart,
                       rbStart, nodeHrb);

    int occ = 0;
    if (hipOccupancyMaxActiveBlocksPerMultiprocessor(&occ, (const void*)tree_reg_kernel, 256, 0) != hipSuccess || occ < 1)
        occ = 1;
    int bpc = occ < 2 ? occ : 2;
    dim3 grid(256 * bpc);

    void* args[] = { (void*)&inputs, (void*)&type_mask, (void*)&Wimg, (void*)&bias,
                     (void*)&order, (void*)&offsets, (void*)&nlev, (void*)&parent,
                     (void*)&rbStart, (void*)&nodeHrb, (void*)&rbCnt, (void*)&xFlag,
                     (void*)&preAct, (void*)&hPack, (void*)&cPack, (void*)&out };
    hipLaunchCooperativeKernel((const void*)tree_reg_kernel, grid, dim3(256), args, 0, stream);
}

// Round 9
// 902.766 us; speedup vs baseline: 1.4587x; 1.2104x over previous
//
#include <hip/hip_runtime.h>
#include <math.h>

typedef unsigned short ushort_t;
typedef unsigned int uint_t;
typedef unsigned long long u64_t;
typedef __attribute__((ext_vector_type(8))) short short8;
typedef __attribute__((ext_vector_type(4))) float f32x4;

#define N_NODES 8192
#define DIM 512
#define KTOT 1024
#define NCOLS 4096
#define BM 128
#define BN 128
#define NTILE (NCOLS / BN)   // 32 column tiles
#define KIT (KTOT / 32)      // 32 k iterations (BK=32)
// Wimg: hi-plane bf16, direct-fragment layout: tile(ntile,it) 128 cols x 32 k
#define WIMG_USHORTS ((size_t)NTILE * KIT * 4096)
#define MAXLEV_LDS 128

__device__ __forceinline__ float sigm(float x) { return 1.0f / (1.0f + __expf(-x)); }
__device__ __forceinline__ float tanh_fast(float x) {
    float ax = fabsf(x);
    float e = __expf(2.0f * ax);
    float t = 1.0f - 2.0f / (e + 1.0f);
    return copysignf(t, x);
}
__device__ __forceinline__ uint_t packf(float f) {
    uint_t u = __float_as_uint(f);
    uint_t hi = u & 0xffff0000u;
    float r = f - __uint_as_float(hi);
    return hi | (__float_as_uint(r) >> 16);
}
__device__ __forceinline__ uint_t rne16(float f) {
    uint_t u = __float_as_uint(f);
    return (u + 0x7fffu + ((u >> 16) & 1u)) >> 16;
}

// split 8 packed (hi|lo) u32 -> hi-frag / lo-frag short8
__device__ __forceinline__ void fragAB_u32(const uint4 w0, const uint4 w1,
                                           short8& hi8, short8& lo8) {
    union { uint_t w[4]; short8 s; } H, L;
    uint_t u[8] = { w0.x, w0.y, w0.z, w0.w, w1.x, w1.y, w1.z, w1.w };
#pragma unroll
    for (int j = 0; j < 4; ++j) {
        H.w[j] = (u[2 * j + 1] & 0xffff0000u) | (u[2 * j] >> 16);
        L.w[j] = (u[2 * j + 1] << 16) | (u[2 * j] & 0xffffu);
    }
    hi8 = H.s; lo8 = L.s;
}

// split 8 fp32 -> hi-frag (trunc) / lo-frag (residual) short8
__device__ __forceinline__ void fragA_f32(const float4 f0, const float4 f1,
                                          short8& hi8, short8& lo8) {
    union { uint_t w[4]; short8 s; } H, L;
    float f[8] = { f0.x, f0.y, f0.z, f0.w, f1.x, f1.y, f1.z, f1.w };
#pragma unroll
    for (int j = 0; j < 4; ++j) {
        float a = f[2 * j], b = f[2 * j + 1];
        uint_t h0 = __float_as_uint(a) & 0xffff0000u;
        uint_t h1 = __float_as_uint(b) & 0xffff0000u;
        float r0 = a - __uint_as_float(h0);
        float r1 = b - __uint_as_float(h1);
        H.w[j] = h1 | (h0 >> 16);
        L.w[j] = (__float_as_uint(r1) & 0xffff0000u) | (__float_as_uint(r0) >> 16);
    }
    hi8 = H.s; lo8 = L.s;
}

// ---------------------------------------------------------------------------
// Prep: weights -> bf16 (hi plane, RNE), direct-fragment image (verified r8)
// ---------------------------------------------------------------------------
__global__ void __launch_bounds__(256) prep_wimg_kernel(
    const float* __restrict__ Wx_iou_v, const float* __restrict__ Wh_iou_v,
    const float* __restrict__ Wx_f_v,   const float* __restrict__ Wh_f_v,
    const float* __restrict__ Wx_iou_l, const float* __restrict__ Wh_iou_l,
    const float* __restrict__ Wx_f_l,   const float* __restrict__ Wh_f_l,
    ushort_t* __restrict__ Wimg)
{
    __shared__ float T[32][132];   // T[kk][jloc]
    int p = blockIdx.x >> 5, it = blockIdx.x & 31;
    int tid = threadIdx.x;
#pragma unroll
    for (int e = 0; e < 16; ++e) {
        int lin = e * 256 + tid;
        int dloc = lin & 15, kk = (lin >> 4) & 31, q = lin >> 9;
        int d = p * 16 + dloc;
        int qq = q & 3; bool lang = q >= 4;
        int k = it * 32 + kk;
        const float* W; int col, stride;
        if (qq < 3) { col = qq * DIM + d; stride = 3 * DIM;
            W = (k < DIM) ? (lang ? Wx_iou_l : Wx_iou_v) : (lang ? Wh_iou_l : Wh_iou_v); }
        else        { col = d; stride = DIM;
            W = (k < DIM) ? (lang ? Wx_f_l : Wx_f_v) : (lang ? Wh_f_l : Wh_f_v); }
        int kr = (k < DIM) ? k : (k - DIM);
        T[kk][dloc * 8 + q] = W[(size_t)kr * stride + col];
    }
    __syncthreads();
    size_t tilebase = (size_t)blockIdx.x * 4096;
#pragma unroll
    for (int gch = 0; gch < 2; ++gch) {
        int gi = gch * 256 + tid;          // uint4 index 0..511
        int col = gi >> 2, gd = gi & 3;
        uint_t wds[4];
#pragma unroll
        for (int i = 0; i < 4; ++i) {
            uint_t v0 = rne16(T[gd * 8 + 2 * i][col]);
            uint_t v1 = rne16(T[gd * 8 + 2 * i + 1][col]);
            wds[i] = (v1 << 16) | v0;
        }
        *(uint4*)(Wimg + tilebase + (size_t)gi * 8) = make_uint4(wds[0], wds[1], wds[2], wds[3]);
    }
}

__global__ void prep_bias_kernel(
    const float* __restrict__ bx_iou_v, const float* __restrict__ bh_iou_v,
    const float* __restrict__ bx_f_v,   const float* __restrict__ bh_f_v,
    const float* __restrict__ bx_iou_l, const float* __restrict__ bh_iou_l,
    const float* __restrict__ bx_f_l,   const float* __restrict__ bh_f_l,
    float* __restrict__ bias)
{
    int j = blockIdx.x * blockDim.x + threadIdx.x;
    if (j >= NCOLS) return;
    int d = j >> 3, q = j & 7;
    int qq = q & 3;
    bool lang = (q & 4) != 0;
    const float* bx; const float* bh; int col;
    if (qq < 3) { col = qq * DIM + d; bx = lang ? bx_iou_l : bx_iou_v; bh = lang ? bh_iou_l : bh_iou_v; }
    else        { col = d;            bx = lang ? bx_f_l  : bx_f_v;   bh = lang ? bh_f_l  : bh_f_v; }
    bias[j] = bx[col] + bh[col];
}

// ---------------------------------------------------------------------------
// Level computation + counting sort + rowblock tables (verified r4-r8)
// ---------------------------------------------------------------------------
__global__ void __launch_bounds__(1024) levels_sort_kernel(
    const int* __restrict__ parent,
    int* __restrict__ order, int* __restrict__ offsets,
    int* __restrict__ counts, int* __restrict__ cursors,
    int* __restrict__ nlev, int* __restrict__ tilestart,
    int* __restrict__ rbStart, int* __restrict__ nodeHrb)
{
    __shared__ int s_level[N_NODES];
    __shared__ int s_assigned;
    __shared__ int s_maxlev;
    int tid = threadIdx.x;
    int pr[8];
#pragma unroll
    for (int ii = 0; ii < 8; ++ii) {
        int i = tid + ii * 1024;
        pr[ii] = parent[i];
        s_level[i] = -1;
    }
    for (int i = tid; i <= N_NODES; i += 1024) counts[i] = 0;
    if (tid == 0) { s_assigned = 0; s_maxlev = 0; }
    __syncthreads();

    for (int pass = 0; pass <= N_NODES; ++pass) {
        int newly = 0;
#pragma unroll
        for (int ii = 0; ii < 8; ++ii) {
            int i = tid + ii * 1024;
            if (s_level[i] < 0) {
                int p = pr[ii];
                if (p == 0) { s_level[i] = 0; newly++; }
                else { int lp = s_level[p - 1]; if (lp >= 0) { s_level[i] = lp + 1; newly++; } }
            }
        }
        if (newly) atomicAdd(&s_assigned, newly);
        __syncthreads();
        int a = s_assigned;
        if (a >= N_NODES) break;
        __syncthreads();
    }

#pragma unroll
    for (int ii = 0; ii < 8; ++ii) {
        int i = tid + ii * 1024;
        int lv = s_level[i];
        atomicAdd(&counts[lv], 1);
        atomicMax(&s_maxlev, lv);
    }
    __syncthreads();
    if (tid == 0) {
        int nl = s_maxlev + 1;
        nlev[0] = nl;
        int off = 0, toff = 0, rb = 0;
        for (int l = 0; l < nl; ++l) {
            offsets[l] = off; cursors[l] = off;
            tilestart[l] = toff; rbStart[l] = rb;
            int mt = (counts[l] + BM - 1) / BM;
            rb += mt;
            toff += mt * NTILE;
            off += counts[l];
        }
        offsets[nl] = off;
        tilestart[nl] = toff;
        rbStart[nl] = rb;
        nlev[1] = toff;   // total fused tiles
    }
    __syncthreads();
#pragma unroll
    for (int ii = 0; ii < 8; ++ii) {
        int i = tid + ii * 1024;
        int lv = s_level[i];
        int pos = atomicAdd(&cursors[lv], 1);
        order[pos] = i;
        nodeHrb[i] = rbStart[lv] + ((pos - offsets[lv]) >> 7);
    }
}

// ---------------------------------------------------------------------------
// Fused worker: per tile x-GEMM (no deps) + parent-wait + h-GEMM + epilogue.
// LDS-free register GEMM; no preAct; fence-free sc1 publishing.
// ---------------------------------------------------------------------------
__global__ void __launch_bounds__(256, 2) tree_fused_kernel(
    const float* __restrict__ inputs, const float* __restrict__ type_mask,
    const ushort_t* __restrict__ Wimg, const float* __restrict__ bias,
    const int* __restrict__ order, const int* __restrict__ offsets,
    const int* __restrict__ nlev, const int* __restrict__ parent,
    const int* __restrict__ rbStart, const int* __restrict__ nodeHrb,
    int* __restrict__ rbCnt,
    uint_t* __restrict__ hPack, uint_t* __restrict__ cPack,
    float* __restrict__ out)
{
    float* cOut = out;
    float* hOut = out + (size_t)N_NODES * DIM;

    __shared__ float eps[BM * 68];       // 34.8 KB epilogue transpose
    __shared__ int s_node[BM];
    __shared__ int s_par[BM];
    __shared__ int s_phrb[BM];
    __shared__ float s_tm[BM][2];
    __shared__ int s_rbs[MAXLEV_LDS];
    __shared__ int s_off[MAXLEV_LDS];

    int tid = threadIdx.x;
    int lane = tid & 63, w = tid >> 6, wr = w >> 1, wc = w & 1;
    int l15 = lane & 15, g = lane >> 4;
    int nl = nlev[0];
    int total = nlev[1];

    int nload = nl + 1; if (nload > MAXLEV_LDS) nload = MAXLEV_LDS;
    for (int i = tid; i < nload; i += 256) { s_rbs[i] = rbStart[i]; s_off[i] = offsets[i]; }
    __syncthreads();

    // B fragment base for this lane (ushort units); tile stride 4096, n stride 512
    const ushort_t* bLane = Wimg + (size_t)(wc * 64 + l15) * 32 + (size_t)g * 8;

#define LDB(RB, tilebase, itt) { \
    _Pragma("unroll") for (int n_ = 0; n_ < 4; ++n_) \
        RB[n_] = *(const uint4*)(bLane + (size_t)(tilebase + (itt)) * 4096 + n_ * 512); }

#define LDA_H(RA, itrel) { \
    _Pragma("unroll") for (int m_ = 0; m_ < 4; ++m_) { \
        const uint4* p_ = (const uint4*)(aBaseH[m_] + (itrel) * 32 + g * 8); \
        RA[m_][0] = p_[0]; RA[m_][1] = p_[1]; } }

#define LDA_X(RA, itt) { \
    _Pragma("unroll") for (int m_ = 0; m_ < 4; ++m_) { \
        const float4* p_ = (const float4*)(aBaseX[m_] + (itt) * 32 + g * 8); \
        RA[m_][0] = p_[0]; RA[m_][1] = p_[1]; } }

#define COMP_H(RA, RB) { \
    short8 bh_[4]; \
    _Pragma("unroll") for (int n_ = 0; n_ < 4; ++n_) { \
        union { uint4 u; short8 s; } c_; c_.u = RB[n_]; bh_[n_] = c_.s; } \
    _Pragma("unroll") for (int m_ = 0; m_ < 4; ++m_) { \
        short8 ah_, al_; fragAB_u32(RA[m_][0], RA[m_][1], ah_, al_); \
        _Pragma("unroll") for (int n_ = 0; n_ < 4; ++n_) { \
            acc[m_][n_] = __builtin_amdgcn_mfma_f32_16x16x32_bf16(ah_, bh_[n_], acc[m_][n_], 0, 0, 0); \
            acc[m_][n_] = __builtin_amdgcn_mfma_f32_16x16x32_bf16(al_, bh_[n_], acc[m_][n_], 0, 0, 0); } } }

#define COMP_X(RA, RB) { \
    short8 bh_[4]; \
    _Pragma("unroll") for (int n_ = 0; n_ < 4; ++n_) { \
        union { uint4 u; short8 s; } c_; c_.u = RB[n_]; bh_[n_] = c_.s; } \
    _Pragma("unroll") for (int m_ = 0; m_ < 4; ++m_) { \
        short8 ah_, al_; fragA_f32(RA[m_][0], RA[m_][1], ah_, al_); \
        _Pragma("unroll") for (int n_ = 0; n_ < 4; ++n_) { \
            acc[m_][n_] = __builtin_amdgcn_mfma_f32_16x16x32_bf16(ah_, bh_[n_], acc[m_][n_], 0, 0, 0); \
            acc[m_][n_] = __builtin_amdgcn_mfma_f32_16x16x32_bf16(al_, bh_[n_], acc[m_][n_], 0, 0, 0); } } }

    for (int t = blockIdx.x; t < total; t += gridDim.x) {
        // locate tile in level-ordered list
        int lev = 0;
        while (lev + 1 < nload && s_rbs[lev + 1] * NTILE <= t) ++lev;
        int lt = t - s_rbs[lev] * NTILE;
        int ntile = lt % NTILE;
        int mt = lt / NTILE;
        int start = s_off[lev];
        int cnt = s_off[lev + 1] - start;
        int jc = ntile * BN;
        int r0 = mt * BM;
        int myhrb = s_rbs[lev] + mt;
        int tbx = ntile * KIT;        // Wimg x half: it 0..15
        int tbh = ntile * KIT + 16;   // Wimg h half: it 16..31

        if (tid < BM) {
            int r = r0 + tid;
            int node = (r < cnt) ? order[start + r] : -1;
            s_node[tid] = node;
            int p = (node >= 0) ? parent[node] : 0;
            s_par[tid] = p;
            s_phrb[tid] = (node >= 0 && p > 0) ? nodeHrb[p - 1] : -1;
            float t0 = 0.f, t1 = 0.f;
            if (node >= 0) { t0 = type_mask[node * 2]; t1 = type_mask[node * 2 + 1]; }
            s_tm[tid][0] = t0; s_tm[tid][1] = t1;
        }
        __syncthreads();

        f32x4 acc[4][4];
#pragma unroll
        for (int m = 0; m < 4; ++m)
#pragma unroll
            for (int n = 0; n < 4; ++n) acc[m][n] = (f32x4)(0.f);

        // ---- x-GEMM (no dependencies): gathered input rows
        {
            const float* aBaseX[4];
#pragma unroll
            for (int m = 0; m < 4; ++m) {
                int nd = s_node[wr * 64 + m * 16 + l15];
                aBaseX[m] = inputs + (size_t)(nd < 0 ? 0 : nd) * DIM;
            }
            float4 xa0[4][2], xa1[4][2]; uint4 xb0[4], xb1[4];
            LDA_X(xa0, 0); LDB(xb0, tbx, 0);
#pragma unroll
            for (int ii = 0; ii < 8; ++ii) {
                int e = 2 * ii, o = e + 1;
                LDA_X(xa1, o); LDB(xb1, tbx, o);
                __builtin_amdgcn_s_setprio(1);
                COMP_X(xa0, xb0);
                __builtin_amdgcn_s_setprio(0);
                if (e + 2 < 16) { LDA_X(xa0, e + 2); LDB(xb0, tbx, e + 2); }
                __builtin_amdgcn_s_setprio(1);
                COMP_X(xa1, xb1);
                __builtin_amdgcn_s_setprio(0);
            }
        }

        // ---- wait for parents' rowblocks, then h-GEMM
        if (lev > 0) {
            if (tid < BM) {
                int hrb = s_phrb[tid];
                if (hrb >= 0) {
                    while (__hip_atomic_load(&rbCnt[hrb], __ATOMIC_RELAXED,
                                             __HIP_MEMORY_SCOPE_AGENT) < NTILE)
                        __builtin_amdgcn_s_sleep(2);
                }
            }
            __syncthreads();

            const uint_t* aBaseH[4];
#pragma unroll
            for (int m = 0; m < 4; ++m) {
                int p = s_par[wr * 64 + m * 16 + l15];
                aBaseH[m] = hPack + (size_t)((p > 0) ? (p - 1) : 0) * DIM;
            }

            uint4 ha0[4][2], ha1[4][2]; uint4 hb0[4], hb1[4];
            LDA_H(ha0, 0); LDB(hb0, tbh, 0);
#pragma unroll
            for (int ii = 0; ii < 8; ++ii) {
                int e = 2 * ii, o = e + 1;
                LDA_H(ha1, o); LDB(hb1, tbh, o);
                __builtin_amdgcn_s_setprio(1);
                COMP_H(ha0, hb0);
                __builtin_amdgcn_s_setprio(0);
                if (e + 2 < 16) { LDA_H(ha0, e + 2); LDB(hb0, tbh, e + 2); }
                __builtin_amdgcn_s_setprio(1);
                COMP_H(ha1, hb1);
                __builtin_amdgcn_s_setprio(0);
            }
        }

        // ---- epilogue: acc transpose + bias + LSTM cell + publish stores
        int cntloc = cnt - r0; if (cntloc > BM) cntloc = BM;
        __syncthreads();
#pragma unroll
        for (int pass = 0; pass < 2; ++pass) {
            if (wc == pass) {
#pragma unroll
                for (int m = 0; m < 4; ++m)
#pragma unroll
                    for (int n = 0; n < 4; ++n) {
                        int row = wr * 64 + m * 16 + g * 4;
                        int c = n * 16 + l15;
#pragma unroll
                        for (int r = 0; r < 4; ++r) eps[(row + r) * 68 + c] = acc[m][n][r];
                    }
            }
            __syncthreads();
#pragma unroll
            for (int e = 0; e < 4; ++e) {
                int task = e * 256 + tid;
                int row = task >> 3, dl = task & 7;
                if (row < cntloc) {
                    int node = s_node[row]; int p = s_par[row];
                    const float* ep = &eps[row * 68 + dl * 8];
                    float4 v0 = *(const float4*)ep;
                    float4 v1 = *(const float4*)(ep + 4);
                    int jb = jc + pass * 64 + dl * 8;
                    float4 b0 = *(const float4*)(bias + jb);
                    float4 b1 = *(const float4*)(bias + jb + 4);
                    int d = jb >> 3;
                    float cp = 0.f;
                    if (p > 0) {
                        uint_t wrd = cPack[(size_t)(p - 1) * DIM + d];
                        cp = __uint_as_float(wrd & 0xffff0000u) + __uint_as_float(wrd << 16);
                    }
                    float cv = sigm(v0.x + b0.x) * tanh_fast(v0.z + b0.z)
                             + sigm(v0.w + b0.w) * cp;
                    float hv = sigm(v0.y + b0.y) * tanh_fast(cv);
                    float cl = sigm(v1.x + b1.x) * tanh_fast(v1.z + b1.z)
                             + sigm(v1.w + b1.w) * cp;
                    float hl = sigm(v1.y + b1.y) * tanh_fast(cl);
                    float tm0 = s_tm[row][0], tm1 = s_tm[row][1];
                    float cn = tm0 * cl + tm1 * cv;
                    float hn2 = tm0 * hl + tm1 * hv;
                    size_t oi = (size_t)node * DIM + d;
                    __hip_atomic_store(&cPack[oi], packf(cn),
                                       __ATOMIC_RELAXED, __HIP_MEMORY_SCOPE_AGENT);
                    __hip_atomic_store(&hPack[oi], packf(hn2),
                                       __ATOMIC_RELAXED, __HIP_MEMORY_SCOPE_AGENT);
                    cOut[oi] = cn;
                    hOut[oi] = hn2;
                }
            }
            __syncthreads();
        }

        __builtin_amdgcn_s_waitcnt(0);   // drain this wave's sc1 stores
        __syncthreads();
        if (tid == 0)
            __hip_atomic_fetch_add(&rbCnt[myhrb], 1, __ATOMIC_RELAXED,
                                   __HIP_MEMORY_SCOPE_AGENT);
    }
#undef LDB
#undef LDA_H
#undef LDA_X
#undef COMP_H
#undef COMP_X
}

// ---------------------------------------------------------------------------
extern "C" void kernel_launch(void* const* d_in, const int* in_sizes, int n_in,
                              void* d_out, int out_size, void* d_ws, size_t ws_size,
                              hipStream_t stream) {
    const float* inputs      = (const float*)d_in[0];
    const float* type_mask   = (const float*)d_in[1];
    const int*   parent      = (const int*)d_in[2];
    const float* W_ioux_vis  = (const float*)d_in[3];
    const float* b_ioux_vis  = (const float*)d_in[4];
    const float* W_iouh_vis  = (const float*)d_in[5];
    const float* b_iouh_vis  = (const float*)d_in[6];
    const float* W_fx_vis    = (const float*)d_in[7];
    const float* b_fx_vis    = (const float*)d_in[8];
    const float* W_fh_vis    = (const float*)d_in[9];
    const float* b_fh_vis    = (const float*)d_in[10];
    const float* W_ioux_lang = (const float*)d_in[11];
    const float* b_ioux_lang = (const float*)d_in[12];
    const float* W_iouh_lang = (const float*)d_in[13];
    const float* b_iouh_lang = (const float*)d_in[14];
    const float* W_fx_lang   = (const float*)d_in[15];
    const float* b_fx_lang   = (const float*)d_in[16];
    const float* W_fh_lang   = (const float*)d_in[17];
    const float* b_fh_lang   = (const float*)d_in[18];

    ushort_t* Wimg = (ushort_t*)d_ws;                      // 8 MB
    float* bias    = (float*)(Wimg + WIMG_USHORTS);
    int* order     = (int*)(bias + NCOLS);
    int* offsets   = order + N_NODES;
    int* counts    = offsets + (N_NODES + 2);
    int* cursors   = counts + (N_NODES + 2);
    int* nlev      = cursors + (N_NODES + 2);
    int* tilestart = nlev + 8;
    int* rbStart   = tilestart + (N_NODES + 2);
    int* nodeHrb   = rbStart + (N_NODES + 2);
    int* rbCnt     = nodeHrb + N_NODES;
    size_t off2 = (size_t)((char*)(rbCnt + 4096) - (char*)d_ws);
    off2 = (off2 + 255) & ~(size_t)255;
    uint_t* hPack = (uint_t*)((char*)d_ws + off2);                       // 16 MB
    uint_t* cPack = hPack + (size_t)N_NODES * DIM;                       // 16 MB

    float* out = (float*)d_out;

    hipMemsetAsync((void*)rbCnt, 0, 4096 * sizeof(int), stream);

    hipLaunchKernelGGL(prep_wimg_kernel, dim3(NTILE * KIT), dim3(256), 0, stream,
                       W_ioux_vis, W_iouh_vis, W_fx_vis, W_fh_vis,
                       W_ioux_lang, W_iouh_lang, W_fx_lang, W_fh_lang, Wimg);
    hipLaunchKernelGGL(prep_bias_kernel, dim3(NCOLS / 256), dim3(256), 0, stream,
                       b_ioux_vis, b_iouh_vis, b_fx_vis, b_fh_vis,
                       b_ioux_lang, b_iouh_lang, b_fx_lang, b_fh_lang, bias);
    hipLaunchKernelGGL(levels_sort_kernel, dim3(1), dim3(1024), 0, stream,
                       parent, order, offsets, counts, cursors, nlev, tilestart,
                       rbStart, nodeHrb);

    int occ = 0;
    if (hipOccupancyMaxActiveBlocksPerMultiprocessor(&occ, (const void*)tree_fused_kernel, 256, 0) != hipSuccess || occ < 1)
        occ = 1;
    int bpc = occ < 2 ? occ : 2;
    dim3 grid(256 * bpc);

    void* args[] = { (void*)&inputs, (void*)&type_mask, (void*)&Wimg, (void*)&bias,
                     (void*)&order, (void*)&offsets, (void*)&nlev, (void*)&parent,
                     (void*)&rbStart, (void*)&nodeHrb, (void*)&rbCnt,
                     (void*)&hPack, (void*)&cPack, (void*)&out };
    hipLaunchCooperativeKernel((const void*)tree_fused_kernel, grid, dim3(256), args, 0, stream);
}

// Round 10
// 902.460 us; speedup vs baseline: 1.4592x; 1.0003x over previous
//
#include <hip/hip_runtime.h>
#include <math.h>

typedef unsigned short ushort_t;
typedef unsigned int uint_t;
typedef unsigned long long u64_t;
typedef __attribute__((ext_vector_type(8))) short short8;
typedef __attribute__((ext_vector_type(4))) float f32x4;

#define N_NODES 8192
#define DIM 512
#define KTOT 1024
#define NCOLS 4096
#define BM 128
#define BN 128
#define NTILE (NCOLS / BN)   // 32 column tiles
#define KIT (KTOT / 32)      // 32 k iterations (BK=32)
// Wimg: hi-plane bf16, direct-fragment layout: tile(ntile,it) 128 cols x 32 k
#define WIMG_USHORTS ((size_t)NTILE * KIT * 4096)
#define MAXLEV_LDS 128

__device__ __forceinline__ float sigm(float x) { return 1.0f / (1.0f + __expf(-x)); }
__device__ __forceinline__ float tanh_fast(float x) {
    float ax = fabsf(x);
    float e = __expf(2.0f * ax);
    float t = 1.0f - 2.0f / (e + 1.0f);
    return copysignf(t, x);
}
__device__ __forceinline__ uint_t packf(float f) {
    uint_t u = __float_as_uint(f);
    uint_t hi = u & 0xffff0000u;
    float r = f - __uint_as_float(hi);
    return hi | (__float_as_uint(r) >> 16);
}
__device__ __forceinline__ uint_t rne16(float f) {
    uint_t u = __float_as_uint(f);
    return (u + 0x7fffu + ((u >> 16) & 1u)) >> 16;
}

// split 8 packed (hi|lo) u32 -> hi-frag / lo-frag short8
__device__ __forceinline__ void fragAB_u32(const uint4 w0, const uint4 w1,
                                           short8& hi8, short8& lo8) {
    union { uint_t w[4]; short8 s; } H, L;
    uint_t u[8] = { w0.x, w0.y, w0.z, w0.w, w1.x, w1.y, w1.z, w1.w };
#pragma unroll
    for (int j = 0; j < 4; ++j) {
        H.w[j] = (u[2 * j + 1] & 0xffff0000u) | (u[2 * j] >> 16);
        L.w[j] = (u[2 * j + 1] << 16) | (u[2 * j] & 0xffffu);
    }
    hi8 = H.s; lo8 = L.s;
}

// split 8 fp32 -> hi-frag (trunc) / lo-frag (residual) short8
__device__ __forceinline__ void fragA_f32(const float4 f0, const float4 f1,
                                          short8& hi8, short8& lo8) {
    union { uint_t w[4]; short8 s; } H, L;
    float f[8] = { f0.x, f0.y, f0.z, f0.w, f1.x, f1.y, f1.z, f1.w };
#pragma unroll
    for (int j = 0; j < 4; ++j) {
        float a = f[2 * j], b = f[2 * j + 1];
        uint_t h0 = __float_as_uint(a) & 0xffff0000u;
        uint_t h1 = __float_as_uint(b) & 0xffff0000u;
        float r0 = a - __uint_as_float(h0);
        float r1 = b - __uint_as_float(h1);
        H.w[j] = h1 | (h0 >> 16);
        L.w[j] = (__float_as_uint(r1) & 0xffff0000u) | (__float_as_uint(r0) >> 16);
    }
    hi8 = H.s; lo8 = L.s;
}

// ---------------------------------------------------------------------------
// Prep: weights -> bf16 (hi plane, RNE), direct-fragment image (verified r8/r9)
// ---------------------------------------------------------------------------
__global__ void __launch_bounds__(256) prep_wimg_kernel(
    const float* __restrict__ Wx_iou_v, const float* __restrict__ Wh_iou_v,
    const float* __restrict__ Wx_f_v,   const float* __restrict__ Wh_f_v,
    const float* __restrict__ Wx_iou_l, const float* __restrict__ Wh_iou_l,
    const float* __restrict__ Wx_f_l,   const float* __restrict__ Wh_f_l,
    ushort_t* __restrict__ Wimg)
{
    __shared__ float T[32][132];   // T[kk][jloc]
    int p = blockIdx.x >> 5, it = blockIdx.x & 31;
    int tid = threadIdx.x;
#pragma unroll
    for (int e = 0; e < 16; ++e) {
        int lin = e * 256 + tid;
        int dloc = lin & 15, kk = (lin >> 4) & 31, q = lin >> 9;
        int d = p * 16 + dloc;
        int qq = q & 3; bool lang = q >= 4;
        int k = it * 32 + kk;
        const float* W; int col, stride;
        if (qq < 3) { col = qq * DIM + d; stride = 3 * DIM;
            W = (k < DIM) ? (lang ? Wx_iou_l : Wx_iou_v) : (lang ? Wh_iou_l : Wh_iou_v); }
        else        { col = d; stride = DIM;
            W = (k < DIM) ? (lang ? Wx_f_l : Wx_f_v) : (lang ? Wh_f_l : Wh_f_v); }
        int kr = (k < DIM) ? k : (k - DIM);
        T[kk][dloc * 8 + q] = W[(size_t)kr * stride + col];
    }
    __syncthreads();
    size_t tilebase = (size_t)blockIdx.x * 4096;
#pragma unroll
    for (int gch = 0; gch < 2; ++gch) {
        int gi = gch * 256 + tid;          // uint4 index 0..511
        int col = gi >> 2, gd = gi & 3;
        uint_t wds[4];
#pragma unroll
        for (int i = 0; i < 4; ++i) {
            uint_t v0 = rne16(T[gd * 8 + 2 * i][col]);
            uint_t v1 = rne16(T[gd * 8 + 2 * i + 1][col]);
            wds[i] = (v1 << 16) | v0;
        }
        *(uint4*)(Wimg + tilebase + (size_t)gi * 8) = make_uint4(wds[0], wds[1], wds[2], wds[3]);
    }
}

__global__ void prep_bias_kernel(
    const float* __restrict__ bx_iou_v, const float* __restrict__ bh_iou_v,
    const float* __restrict__ bx_f_v,   const float* __restrict__ bh_f_v,
    const float* __restrict__ bx_iou_l, const float* __restrict__ bh_iou_l,
    const float* __restrict__ bx_f_l,   const float* __restrict__ bh_f_l,
    float* __restrict__ bias)
{
    int j = blockIdx.x * blockDim.x + threadIdx.x;
    if (j >= NCOLS) return;
    int d = j >> 3, q = j & 7;
    int qq = q & 3;
    bool lang = (q & 4) != 0;
    const float* bx; const float* bh; int col;
    if (qq < 3) { col = qq * DIM + d; bx = lang ? bx_iou_l : bx_iou_v; bh = lang ? bh_iou_l : bh_iou_v; }
    else        { col = d;            bx = lang ? bx_f_l  : bx_f_v;   bh = lang ? bh_f_l  : bh_f_v; }
    bias[j] = bx[col] + bh[col];
}

// ---------------------------------------------------------------------------
// Level computation + counting sort + rowblock tables (verified r4-r9)
// ---------------------------------------------------------------------------
__global__ void __launch_bounds__(1024) levels_sort_kernel(
    const int* __restrict__ parent,
    int* __restrict__ order, int* __restrict__ offsets,
    int* __restrict__ counts, int* __restrict__ cursors,
    int* __restrict__ nlev, int* __restrict__ tilestart,
    int* __restrict__ rbStart, int* __restrict__ nodeHrb)
{
    __shared__ int s_level[N_NODES];
    __shared__ int s_assigned;
    __shared__ int s_maxlev;
    int tid = threadIdx.x;
    int pr[8];
#pragma unroll
    for (int ii = 0; ii < 8; ++ii) {
        int i = tid + ii * 1024;
        pr[ii] = parent[i];
        s_level[i] = -1;
    }
    for (int i = tid; i <= N_NODES; i += 1024) counts[i] = 0;
    if (tid == 0) { s_assigned = 0; s_maxlev = 0; }
    __syncthreads();

    for (int pass = 0; pass <= N_NODES; ++pass) {
        int newly = 0;
#pragma unroll
        for (int ii = 0; ii < 8; ++ii) {
            int i = tid + ii * 1024;
            if (s_level[i] < 0) {
                int p = pr[ii];
                if (p == 0) { s_level[i] = 0; newly++; }
                else { int lp = s_level[p - 1]; if (lp >= 0) { s_level[i] = lp + 1; newly++; } }
            }
        }
        if (newly) atomicAdd(&s_assigned, newly);
        __syncthreads();
        int a = s_assigned;
        if (a >= N_NODES) break;
        __syncthreads();
    }

#pragma unroll
    for (int ii = 0; ii < 8; ++ii) {
        int i = tid + ii * 1024;
        int lv = s_level[i];
        atomicAdd(&counts[lv], 1);
        atomicMax(&s_maxlev, lv);
    }
    __syncthreads();
    if (tid == 0) {
        int nl = s_maxlev + 1;
        nlev[0] = nl;
        int off = 0, toff = 0, rb = 0;
        for (int l = 0; l < nl; ++l) {
            offsets[l] = off; cursors[l] = off;
            tilestart[l] = toff; rbStart[l] = rb;
            int mt = (counts[l] + BM - 1) / BM;
            rb += mt;
            toff += mt * NTILE;
            off += counts[l];
        }
        offsets[nl] = off;
        tilestart[nl] = toff;
        rbStart[nl] = rb;
        nlev[1] = toff;   // total fused tiles
    }
    __syncthreads();
#pragma unroll
    for (int ii = 0; ii < 8; ++ii) {
        int i = tid + ii * 1024;
        int lv = s_level[i];
        int pos = atomicAdd(&cursors[lv], 1);
        order[pos] = i;
        nodeHrb[i] = rbStart[lv] + ((pos - offsets[lv]) >> 7);
    }
}

// ---------------------------------------------------------------------------
// Fused worker (r9 structure): per tile x-GEMM + range-wait + h-GEMM + epilogue.
// LDS-free register GEMM; fence-free sc1 publishing; deduped low-rate polling.
// ---------------------------------------------------------------------------
__global__ void __launch_bounds__(256, 2) tree_fused_kernel(
    const float* __restrict__ inputs, const float* __restrict__ type_mask,
    const ushort_t* __restrict__ Wimg, const float* __restrict__ bias,
    const int* __restrict__ order, const int* __restrict__ offsets,
    const int* __restrict__ nlev, const int* __restrict__ parent,
    const int* __restrict__ rbStart, const int* __restrict__ nodeHrb,
    int* __restrict__ rbCnt,
    uint_t* __restrict__ hPack, uint_t* __restrict__ cPack,
    float* __restrict__ out)
{
    float* cOut = out;
    float* hOut = out + (size_t)N_NODES * DIM;

    __shared__ float eps[BM * 68];       // 34.8 KB epilogue transpose
    __shared__ int s_node[BM];
    __shared__ int s_par[BM];
    __shared__ float s_tm[BM][2];
    __shared__ int s_rbs[MAXLEV_LDS];
    __shared__ int s_off[MAXLEV_LDS];

    int tid = threadIdx.x;
    int lane = tid & 63, w = tid >> 6, wr = w >> 1, wc = w & 1;
    int l15 = lane & 15, g = lane >> 4;
    int nl = nlev[0];
    int total = nlev[1];

    int nload = nl + 1; if (nload > MAXLEV_LDS) nload = MAXLEV_LDS;
    for (int i = tid; i < nload; i += 256) { s_rbs[i] = rbStart[i]; s_off[i] = offsets[i]; }
    __syncthreads();

    // B fragment base for this lane (ushort units); tile stride 4096, n stride 512
    const ushort_t* bLane = Wimg + (size_t)(wc * 64 + l15) * 32 + (size_t)g * 8;

#define LDB(RB, tilebase, itt) { \
    _Pragma("unroll") for (int n_ = 0; n_ < 4; ++n_) \
        RB[n_] = *(const uint4*)(bLane + (size_t)(tilebase + (itt)) * 4096 + n_ * 512); }

#define LDA_H(RA, itrel) { \
    _Pragma("unroll") for (int m_ = 0; m_ < 4; ++m_) { \
        const uint4* p_ = (const uint4*)(aBaseH[m_] + (itrel) * 32 + g * 8); \
        RA[m_][0] = p_[0]; RA[m_][1] = p_[1]; } }

#define LDA_X(RA, itt) { \
    _Pragma("unroll") for (int m_ = 0; m_ < 4; ++m_) { \
        const float4* p_ = (const float4*)(aBaseX[m_] + (itt) * 32 + g * 8); \
        RA[m_][0] = p_[0]; RA[m_][1] = p_[1]; } }

#define COMP_H(RA, RB) { \
    short8 bh_[4]; \
    _Pragma("unroll") for (int n_ = 0; n_ < 4; ++n_) { \
        union { uint4 u; short8 s; } c_; c_.u = RB[n_]; bh_[n_] = c_.s; } \
    _Pragma("unroll") for (int m_ = 0; m_ < 4; ++m_) { \
        short8 ah_, al_; fragAB_u32(RA[m_][0], RA[m_][1], ah_, al_); \
        _Pragma("unroll") for (int n_ = 0; n_ < 4; ++n_) { \
            acc[m_][n_] = __builtin_amdgcn_mfma_f32_16x16x32_bf16(ah_, bh_[n_], acc[m_][n_], 0, 0, 0); \
            acc[m_][n_] = __builtin_amdgcn_mfma_f32_16x16x32_bf16(al_, bh_[n_], acc[m_][n_], 0, 0, 0); } } }

#define COMP_X(RA, RB) { \
    short8 bh_[4]; \
    _Pragma("unroll") for (int n_ = 0; n_ < 4; ++n_) { \
        union { uint4 u; short8 s; } c_; c_.u = RB[n_]; bh_[n_] = c_.s; } \
    _Pragma("unroll") for (int m_ = 0; m_ < 4; ++m_) { \
        short8 ah_, al_; fragA_f32(RA[m_][0], RA[m_][1], ah_, al_); \
        _Pragma("unroll") for (int n_ = 0; n_ < 4; ++n_) { \
            acc[m_][n_] = __builtin_amdgcn_mfma_f32_16x16x32_bf16(ah_, bh_[n_], acc[m_][n_], 0, 0, 0); \
            acc[m_][n_] = __builtin_amdgcn_mfma_f32_16x16x32_bf16(al_, bh_[n_], acc[m_][n_], 0, 0, 0); } } }

    for (int t = blockIdx.x; t < total; t += gridDim.x) {
        // locate tile in level-ordered list
        int lev = 0;
        while (lev + 1 < nload && s_rbs[lev + 1] * NTILE <= t) ++lev;
        int lt = t - s_rbs[lev] * NTILE;
        int ntile = lt % NTILE;
        int mt = lt / NTILE;
        int start = s_off[lev];
        int cnt = s_off[lev + 1] - start;
        int jc = ntile * BN;
        int r0 = mt * BM;
        int myhrb = s_rbs[lev] + mt;
        int tbx = ntile * KIT;        // Wimg x half: it 0..15
        int tbh = ntile * KIT + 16;   // Wimg h half: it 16..31

        if (tid < BM) {
            int r = r0 + tid;
            int node = (r < cnt) ? order[start + r] : -1;
            s_node[tid] = node;
            int p = (node >= 0) ? parent[node] : 0;
            s_par[tid] = p;
            float t0 = 0.f, t1 = 0.f;
            if (node >= 0) { t0 = type_mask[node * 2]; t1 = type_mask[node * 2 + 1]; }
            s_tm[tid][0] = t0; s_tm[tid][1] = t1;
        }
        __syncthreads();

        f32x4 acc[4][4];
#pragma unroll
        for (int m = 0; m < 4; ++m)
#pragma unroll
            for (int n = 0; n < 4; ++n) acc[m][n] = (f32x4)(0.f);

        // ---- x-GEMM (no dependencies): gathered input rows
        {
            const float* aBaseX[4];
#pragma unroll
            for (int m = 0; m < 4; ++m) {
                int nd = s_node[wr * 64 + m * 16 + l15];
                aBaseX[m] = inputs + (size_t)(nd < 0 ? 0 : nd) * DIM;
            }
            float4 xa0[4][2], xa1[4][2]; uint4 xb0[4], xb1[4];
            LDA_X(xa0, 0); LDB(xb0, tbx, 0);
#pragma unroll
            for (int ii = 0; ii < 8; ++ii) {
                int e = 2 * ii, o = e + 1;
                LDA_X(xa1, o); LDB(xb1, tbx, o);
                __builtin_amdgcn_s_setprio(1);
                COMP_X(xa0, xb0);
                __builtin_amdgcn_s_setprio(0);
                if (e + 2 < 16) { LDA_X(xa0, e + 2); LDB(xb0, tbx, e + 2); }
                __builtin_amdgcn_s_setprio(1);
                COMP_X(xa1, xb1);
                __builtin_amdgcn_s_setprio(0);
            }
        }

        // ---- range-wait on previous level's rowblocks, then h-GEMM
        if (lev > 0) {
            uint4 ha0[4][2], ha1[4][2]; uint4 hb0[4], hb1[4];
            // prefetch first two B k-iters BEFORE the wait (no dependency)
            LDB(hb0, tbh, 0); LDB(hb1, tbh, 1);

            {
                int rb0 = s_rbs[lev - 1];
                int nPrev = s_rbs[lev] - rb0;     // <= 64
                if (tid < nPrev) {
                    while (__hip_atomic_load(&rbCnt[rb0 + tid], __ATOMIC_RELAXED,
                                             __HIP_MEMORY_SCOPE_AGENT) < NTILE)
                        __builtin_amdgcn_s_sleep(16);
                }
            }
            __syncthreads();

            const uint_t* aBaseH[4];
#pragma unroll
            for (int m = 0; m < 4; ++m) {
                int p = s_par[wr * 64 + m * 16 + l15];
                aBaseH[m] = hPack + (size_t)((p > 0) ? (p - 1) : 0) * DIM;
            }

            LDA_H(ha0, 0); LDA_H(ha1, 1);
#pragma unroll
            for (int ii = 0; ii < 8; ++ii) {
                int e = 2 * ii, o = e + 1;
                __builtin_amdgcn_s_setprio(1);
                COMP_H(ha0, hb0);
                __builtin_amdgcn_s_setprio(0);
                if (e + 2 < 16) { LDA_H(ha0, e + 2); LDB(hb0, tbh, e + 2); }
                __builtin_amdgcn_s_setprio(1);
                COMP_H(ha1, hb1);
                __builtin_amdgcn_s_setprio(0);
                if (o + 2 < 16) { LDA_H(ha1, o + 2); LDB(hb1, tbh, o + 2); }
            }
        }

        // ---- epilogue: acc transpose + bias + LSTM cell + publish stores
        int cntloc = cnt - r0; if (cntloc > BM) cntloc = BM;
        __syncthreads();
#pragma unroll
        for (int pass = 0; pass < 2; ++pass) {
            if (wc == pass) {
#pragma unroll
                for (int m = 0; m < 4; ++m)
#pragma unroll
                    for (int n = 0; n < 4; ++n) {
                        int row = wr * 64 + m * 16 + g * 4;
                        int c = n * 16 + l15;
#pragma unroll
                        for (int r = 0; r < 4; ++r) eps[(row + r) * 68 + c] = acc[m][n][r];
                    }
            }
            __syncthreads();
#pragma unroll
            for (int e = 0; e < 4; ++e) {
                int task = e * 256 + tid;
                int row = task >> 3, dl = task & 7;
                if (row < cntloc) {
                    int node = s_node[row]; int p = s_par[row];
                    const float* ep = &eps[row * 68 + dl * 8];
                    float4 v0 = *(const float4*)ep;
                    float4 v1 = *(const float4*)(ep + 4);
                    int jb = jc + pass * 64 + dl * 8;
                    float4 b0 = *(const float4*)(bias + jb);
                    float4 b1 = *(const float4*)(bias + jb + 4);
                    int d = jb >> 3;
                    float cp = 0.f;
                    if (p > 0) {
                        uint_t wrd = cPack[(size_t)(p - 1) * DIM + d];
                        cp = __uint_as_float(wrd & 0xffff0000u) + __uint_as_float(wrd << 16);
                    }
                    float cv = sigm(v0.x + b0.x) * tanh_fast(v0.z + b0.z)
                             + sigm(v0.w + b0.w) * cp;
                    float hv = sigm(v0.y + b0.y) * tanh_fast(cv);
                    float cl = sigm(v1.x + b1.x) * tanh_fast(v1.z + b1.z)
                             + sigm(v1.w + b1.w) * cp;
                    float hl = sigm(v1.y + b1.y) * tanh_fast(cl);
                    float tm0 = s_tm[row][0], tm1 = s_tm[row][1];
                    float cn = tm0 * cl + tm1 * cv;
                    float hn2 = tm0 * hl + tm1 * hv;
                    size_t oi = (size_t)node * DIM + d;
                    __hip_atomic_store(&cPack[oi], packf(cn),
                                       __ATOMIC_RELAXED, __HIP_MEMORY_SCOPE_AGENT);
                    __hip_atomic_store(&hPack[oi], packf(hn2),
                                       __ATOMIC_RELAXED, __HIP_MEMORY_SCOPE_AGENT);
                    cOut[oi] = cn;
                    hOut[oi] = hn2;
                }
            }
            __syncthreads();
        }

        __builtin_amdgcn_s_waitcnt(0);   // drain this wave's sc1 stores
        __syncthreads();
        if (tid == 0)
            __hip_atomic_fetch_add(&rbCnt[myhrb], 1, __ATOMIC_RELAXED,
                                   __HIP_MEMORY_SCOPE_AGENT);
    }
#undef LDB
#undef LDA_H
#undef LDA_X
#undef COMP_H
#undef COMP_X
}

// ---------------------------------------------------------------------------
extern "C" void kernel_launch(void* const* d_in, const int* in_sizes, int n_in,
                              void* d_out, int out_size, void* d_ws, size_t ws_size,
                              hipStream_t stream) {
    const float* inputs      = (const float*)d_in[0];
    const float* type_mask   = (const float*)d_in[1];
    const int*   parent      = (const int*)d_in[2];
    const float* W_ioux_vis  = (const float*)d_in[3];
    const float* b_ioux_vis  = (const float*)d_in[4];
    const float* W_iouh_vis  = (const float*)d_in[5];
    const float* b_iouh_vis  = (const float*)d_in[6];
    const float* W_fx_vis    = (const float*)d_in[7];
    const float* b_fx_vis    = (const float*)d_in[8];
    const float* W_fh_vis    = (const float*)d_in[9];
    const float* b_fh_vis    = (const float*)d_in[10];
    const float* W_ioux_lang = (const float*)d_in[11];
    const float* b_ioux_lang = (const float*)d_in[12];
    const float* W_iouh_lang = (const float*)d_in[13];
    const float* b_iouh_lang = (const float*)d_in[14];
    const float* W_fx_lang   = (const float*)d_in[15];
    const float* b_fx_lang   = (const float*)d_in[16];
    const float* W_fh_lang   = (const float*)d_in[17];
    const float* b_fh_lang   = (const float*)d_in[18];

    ushort_t* Wimg = (ushort_t*)d_ws;                      // 8 MB
    float* bias    = (float*)(Wimg + WIMG_USHORTS);
    int* order     = (int*)(bias + NCOLS);
    int* offsets   = order + N_NODES;
    int* counts    = offsets + (N_NODES + 2);
    int* cursors   = counts + (N_NODES + 2);
    int* nlev      = cursors + (N_NODES + 2);
    int* tilestart = nlev + 8;
    int* rbStart   = tilestart + (N_NODES + 2);
    int* nodeHrb   = rbStart + (N_NODES + 2);
    int* rbCnt     = nodeHrb + N_NODES;
    size_t off2 = (size_t)((char*)(rbCnt + 4096) - (char*)d_ws);
    off2 = (off2 + 255) & ~(size_t)255;
    uint_t* hPack = (uint_t*)((char*)d_ws + off2);                       // 16 MB
    uint_t* cPack = hPack + (size_t)N_NODES * DIM;                       // 16 MB

    float* out = (float*)d_out;

    hipMemsetAsync((void*)rbCnt, 0, 4096 * sizeof(int), stream);

    hipLaunchKernelGGL(prep_wimg_kernel, dim3(NTILE * KIT), dim3(256), 0, stream,
                       W_ioux_vis, W_iouh_vis, W_fx_vis, W_fh_vis,
                       W_ioux_lang, W_iouh_lang, W_fx_lang, W_fh_lang, Wimg);
    hipLaunchKernelGGL(prep_bias_kernel, dim3(NCOLS / 256), dim3(256), 0, stream,
                       b_ioux_vis, b_iouh_vis, b_fx_vis, b_fh_vis,
                       b_ioux_lang, b_iouh_lang, b_fx_lang, b_fh_lang, bias);
    hipLaunchKernelGGL(levels_sort_kernel, dim3(1), dim3(1024), 0, stream,
                       parent, order, offsets, counts, cursors, nlev, tilestart,
                       rbStart, nodeHrb);

    int occ = 0;
    if (hipOccupancyMaxActiveBlocksPerMultiprocessor(&occ, (const void*)tree_fused_kernel, 256, 0) != hipSuccess || occ < 1)
        occ = 1;
    int bpc = occ < 2 ? occ : 2;
    dim3 grid(256 * bpc);

    void* args[] = { (void*)&inputs, (void*)&type_mask, (void*)&Wimg, (void*)&bias,
                     (void*)&order, (void*)&offsets, (void*)&nlev, (void*)&parent,
                     (void*)&rbStart, (void*)&nodeHrb, (void*)&rbCnt,
                     (void*)&hPack, (void*)&cPack, (void*)&out };
    hipLaunchCooperativeKernel((const void*)tree_fused_kernel, grid, dim3(256), args, 0, stream);
}

// Round 11
// 815.137 us; speedup vs baseline: 1.6155x; 1.1071x over previous
//
#include <hip/hip_runtime.h>
#include <math.h>

typedef unsigned short ushort_t;
typedef unsigned int uint_t;
typedef unsigned long long u64_t;
typedef __attribute__((ext_vector_type(8))) short short8;
typedef __attribute__((ext_vector_type(4))) float f32x4;

#define N_NODES 8192
#define DIM 512
#define KTOT 1024
#define NCOLS 4096
#define BM 128
#define BN 128
#define NTILE (NCOLS / BN)   // 32 column tiles
#define KIT (KTOT / 32)      // 32 k iterations (BK=32)
// Wimg: hi-plane bf16, direct-fragment layout: tile(ntile,it) 128 cols x 32 k
#define WIMG_USHORTS ((size_t)NTILE * KIT * 4096)
#define MAXLEV_LDS 128

__device__ __forceinline__ float sigm(float x) { return 1.0f / (1.0f + __expf(-x)); }
__device__ __forceinline__ float tanh_fast(float x) {
    float ax = fabsf(x);
    float e = __expf(2.0f * ax);
    float t = 1.0f - 2.0f / (e + 1.0f);
    return copysignf(t, x);
}
__device__ __forceinline__ uint_t packf(float f) {
    uint_t u = __float_as_uint(f);
    uint_t hi = u & 0xffff0000u;
    float r = f - __uint_as_float(hi);
    return hi | (__float_as_uint(r) >> 16);
}
__device__ __forceinline__ uint_t rne16(float f) {
    uint_t u = __float_as_uint(f);
    return (u + 0x7fffu + ((u >> 16) & 1u)) >> 16;
}

// split 8 packed (hi|lo) u32 -> hi-frag / lo-frag short8
__device__ __forceinline__ void fragAB_u32(const uint4 w0, const uint4 w1,
                                           short8& hi8, short8& lo8) {
    union { uint_t w[4]; short8 s; } H, L;
    uint_t u[8] = { w0.x, w0.y, w0.z, w0.w, w1.x, w1.y, w1.z, w1.w };
#pragma unroll
    for (int j = 0; j < 4; ++j) {
        H.w[j] = (u[2 * j + 1] & 0xffff0000u) | (u[2 * j] >> 16);
        L.w[j] = (u[2 * j + 1] << 16) | (u[2 * j] & 0xffffu);
    }
    hi8 = H.s; lo8 = L.s;
}

// split 8 fp32 -> hi-frag (trunc) / lo-frag (residual) short8
__device__ __forceinline__ void fragA_f32(const float4 f0, const float4 f1,
                                          short8& hi8, short8& lo8) {
    union { uint_t w[4]; short8 s; } H, L;
    float f[8] = { f0.x, f0.y, f0.z, f0.w, f1.x, f1.y, f1.z, f1.w };
#pragma unroll
    for (int j = 0; j < 4; ++j) {
        float a = f[2 * j], b = f[2 * j + 1];
        uint_t h0 = __float_as_uint(a) & 0xffff0000u;
        uint_t h1 = __float_as_uint(b) & 0xffff0000u;
        float r0 = a - __uint_as_float(h0);
        float r1 = b - __uint_as_float(h1);
        H.w[j] = h1 | (h0 >> 16);
        L.w[j] = (__float_as_uint(r1) & 0xffff0000u) | (__float_as_uint(r0) >> 16);
    }
    hi8 = H.s; lo8 = L.s;
}

// ---------------------------------------------------------------------------
// Prep: weights -> bf16 (hi plane, RNE), direct-fragment image (verified r8-r10)
// ---------------------------------------------------------------------------
__global__ void __launch_bounds__(256) prep_wimg_kernel(
    const float* __restrict__ Wx_iou_v, const float* __restrict__ Wh_iou_v,
    const float* __restrict__ Wx_f_v,   const float* __restrict__ Wh_f_v,
    const float* __restrict__ Wx_iou_l, const float* __restrict__ Wh_iou_l,
    const float* __restrict__ Wx_f_l,   const float* __restrict__ Wh_f_l,
    ushort_t* __restrict__ Wimg)
{
    __shared__ float T[32][132];   // T[kk][jloc]
    int p = blockIdx.x >> 5, it = blockIdx.x & 31;
    int tid = threadIdx.x;
#pragma unroll
    for (int e = 0; e < 16; ++e) {
        int lin = e * 256 + tid;
        int dloc = lin & 15, kk = (lin >> 4) & 31, q = lin >> 9;
        int d = p * 16 + dloc;
        int qq = q & 3; bool lang = q >= 4;
        int k = it * 32 + kk;
        const float* W; int col, stride;
        if (qq < 3) { col = qq * DIM + d; stride = 3 * DIM;
            W = (k < DIM) ? (lang ? Wx_iou_l : Wx_iou_v) : (lang ? Wh_iou_l : Wh_iou_v); }
        else        { col = d; stride = DIM;
            W = (k < DIM) ? (lang ? Wx_f_l : Wx_f_v) : (lang ? Wh_f_l : Wh_f_v); }
        int kr = (k < DIM) ? k : (k - DIM);
        T[kk][dloc * 8 + q] = W[(size_t)kr * stride + col];
    }
    __syncthreads();
    size_t tilebase = (size_t)blockIdx.x * 4096;
#pragma unroll
    for (int gch = 0; gch < 2; ++gch) {
        int gi = gch * 256 + tid;          // uint4 index 0..511
        int col = gi >> 2, gd = gi & 3;
        uint_t wds[4];
#pragma unroll
        for (int i = 0; i < 4; ++i) {
            uint_t v0 = rne16(T[gd * 8 + 2 * i][col]);
            uint_t v1 = rne16(T[gd * 8 + 2 * i + 1][col]);
            wds[i] = (v1 << 16) | v0;
        }
        *(uint4*)(Wimg + tilebase + (size_t)gi * 8) = make_uint4(wds[0], wds[1], wds[2], wds[3]);
    }
}

__global__ void prep_bias_kernel(
    const float* __restrict__ bx_iou_v, const float* __restrict__ bh_iou_v,
    const float* __restrict__ bx_f_v,   const float* __restrict__ bh_f_v,
    const float* __restrict__ bx_iou_l, const float* __restrict__ bh_iou_l,
    const float* __restrict__ bx_f_l,   const float* __restrict__ bh_f_l,
    float* __restrict__ bias)
{
    int j = blockIdx.x * blockDim.x + threadIdx.x;
    if (j >= NCOLS) return;
    int d = j >> 3, q = j & 7;
    int qq = q & 3;
    bool lang = (q & 4) != 0;
    const float* bx; const float* bh; int col;
    if (qq < 3) { col = qq * DIM + d; bx = lang ? bx_iou_l : bx_iou_v; bh = lang ? bh_iou_l : bh_iou_v; }
    else        { col = d;            bx = lang ? bx_f_l  : bx_f_v;   bh = lang ? bh_f_l  : bh_f_v; }
    bias[j] = bx[col] + bh[col];
}

// ---------------------------------------------------------------------------
// Level computation + counting sort + rowblock tables (verified r4-r10)
// ---------------------------------------------------------------------------
__global__ void __launch_bounds__(1024) levels_sort_kernel(
    const int* __restrict__ parent,
    int* __restrict__ order, int* __restrict__ offsets,
    int* __restrict__ counts, int* __restrict__ cursors,
    int* __restrict__ nlev, int* __restrict__ tilestart,
    int* __restrict__ rbStart, int* __restrict__ nodeHrb)
{
    __shared__ int s_level[N_NODES];
    __shared__ int s_assigned;
    __shared__ int s_maxlev;
    int tid = threadIdx.x;
    int pr[8];
#pragma unroll
    for (int ii = 0; ii < 8; ++ii) {
        int i = tid + ii * 1024;
        pr[ii] = parent[i];
        s_level[i] = -1;
    }
    for (int i = tid; i <= N_NODES; i += 1024) counts[i] = 0;
    if (tid == 0) { s_assigned = 0; s_maxlev = 0; }
    __syncthreads();

    for (int pass = 0; pass <= N_NODES; ++pass) {
        int newly = 0;
#pragma unroll
        for (int ii = 0; ii < 8; ++ii) {
            int i = tid + ii * 1024;
            if (s_level[i] < 0) {
                int p = pr[ii];
                if (p == 0) { s_level[i] = 0; newly++; }
                else { int lp = s_level[p - 1]; if (lp >= 0) { s_level[i] = lp + 1; newly++; } }
            }
        }
        if (newly) atomicAdd(&s_assigned, newly);
        __syncthreads();
        int a = s_assigned;
        if (a >= N_NODES) break;
        __syncthreads();
    }

#pragma unroll
    for (int ii = 0; ii < 8; ++ii) {
        int i = tid + ii * 1024;
        int lv = s_level[i];
        atomicAdd(&counts[lv], 1);
        atomicMax(&s_maxlev, lv);
    }
    __syncthreads();
    if (tid == 0) {
        int nl = s_maxlev + 1;
        nlev[0] = nl;
        int off = 0, toff = 0, rb = 0;
        for (int l = 0; l < nl; ++l) {
            offsets[l] = off; cursors[l] = off;
            tilestart[l] = toff; rbStart[l] = rb;
            int mt = (counts[l] + BM - 1) / BM;
            rb += mt;
            toff += mt * NTILE;
            off += counts[l];
        }
        offsets[nl] = off;
        tilestart[nl] = toff;
        rbStart[nl] = rb;
        nlev[1] = toff;   // total fused tiles
    }
    __syncthreads();
#pragma unroll
    for (int ii = 0; ii < 8; ++ii) {
        int i = tid + ii * 1024;
        int lv = s_level[i];
        int pos = atomicAdd(&cursors[lv], 1);
        order[pos] = i;
        nodeHrb[i] = rbStart[lv] + ((pos - offsets[lv]) >> 7);
    }
}

// ---------------------------------------------------------------------------
// Fused worker (r10 base) + column-chunk pipelining: per-(level,ntile)
// counters; the h-GEMM k-loop chases the parent level's column wavefront.
// ---------------------------------------------------------------------------
__global__ void __launch_bounds__(256, 2) tree_fused_kernel(
    const float* __restrict__ inputs, const float* __restrict__ type_mask,
    const ushort_t* __restrict__ Wimg, const float* __restrict__ bias,
    const int* __restrict__ order, const int* __restrict__ offsets,
    const int* __restrict__ nlev, const int* __restrict__ parent,
    const int* __restrict__ rbStart,
    int* __restrict__ colCnt,
    uint_t* __restrict__ hPack, uint_t* __restrict__ cPack,
    float* __restrict__ out)
{
    float* cOut = out;
    float* hOut = out + (size_t)N_NODES * DIM;

    __shared__ float eps[BM * 68];       // 34.8 KB epilogue transpose
    __shared__ int s_node[BM];
    __shared__ int s_par[BM];
    __shared__ float s_tm[BM][2];
    __shared__ int s_rbs[MAXLEV_LDS];
    __shared__ int s_off[MAXLEV_LDS];
    __shared__ int s_cok[32];
    __shared__ int s_ok[8];

    int tid = threadIdx.x;
    int lane = tid & 63, w = tid >> 6, wr = w >> 1, wc = w & 1;
    int l15 = lane & 15, g = lane >> 4;
    int nl = nlev[0];
    int total = nlev[1];

    int nload = nl + 1; if (nload > MAXLEV_LDS) nload = MAXLEV_LDS;
    for (int i = tid; i < nload; i += 256) { s_rbs[i] = rbStart[i]; s_off[i] = offsets[i]; }
    __syncthreads();

    // B fragment base for this lane (ushort units); tile stride 4096, n stride 512
    const ushort_t* bLane = Wimg + (size_t)(wc * 64 + l15) * 32 + (size_t)g * 8;

#define LDB(RB, tilebase, itt) { \
    _Pragma("unroll") for (int n_ = 0; n_ < 4; ++n_) \
        RB[n_] = *(const uint4*)(bLane + (size_t)(tilebase + (itt)) * 4096 + n_ * 512); }

#define LDA_H(RA, itrel) { \
    _Pragma("unroll") for (int m_ = 0; m_ < 4; ++m_) { \
        const uint4* p_ = (const uint4*)(aBaseH[m_] + (itrel) * 32 + g * 8); \
        RA[m_][0] = p_[0]; RA[m_][1] = p_[1]; } }

#define LDA_X(RA, itt) { \
    _Pragma("unroll") for (int m_ = 0; m_ < 4; ++m_) { \
        const float4* p_ = (const float4*)(aBaseX[m_] + (itt) * 32 + g * 8); \
        RA[m_][0] = p_[0]; RA[m_][1] = p_[1]; } }

#define COMP_H(RA, RB) { \
    short8 bh_[4]; \
    _Pragma("unroll") for (int n_ = 0; n_ < 4; ++n_) { \
        union { uint4 u; short8 s; } c_; c_.u = RB[n_]; bh_[n_] = c_.s; } \
    _Pragma("unroll") for (int m_ = 0; m_ < 4; ++m_) { \
        short8 ah_, al_; fragAB_u32(RA[m_][0], RA[m_][1], ah_, al_); \
        _Pragma("unroll") for (int n_ = 0; n_ < 4; ++n_) { \
            acc[m_][n_] = __builtin_amdgcn_mfma_f32_16x16x32_bf16(ah_, bh_[n_], acc[m_][n_], 0, 0, 0); \
            acc[m_][n_] = __builtin_amdgcn_mfma_f32_16x16x32_bf16(al_, bh_[n_], acc[m_][n_], 0, 0, 0); } } }

#define COMP_X(RA, RB) { \
    short8 bh_[4]; \
    _Pragma("unroll") for (int n_ = 0; n_ < 4; ++n_) { \
        union { uint4 u; short8 s; } c_; c_.u = RB[n_]; bh_[n_] = c_.s; } \
    _Pragma("unroll") for (int m_ = 0; m_ < 4; ++m_) { \
        short8 ah_, al_; fragA_f32(RA[m_][0], RA[m_][1], ah_, al_); \
        _Pragma("unroll") for (int n_ = 0; n_ < 4; ++n_) { \
            acc[m_][n_] = __builtin_amdgcn_mfma_f32_16x16x32_bf16(ah_, bh_[n_], acc[m_][n_], 0, 0, 0); \
            acc[m_][n_] = __builtin_amdgcn_mfma_f32_16x16x32_bf16(al_, bh_[n_], acc[m_][n_], 0, 0, 0); } } }

// barrier-disciplined wait for column group gq (parent ntiles [4gq,4gq+4))
#define WAIT_GROUPS(colPrev, nPrev, gq) { \
    for (;;) { \
        if (tid < 32) \
            s_cok[tid] = (__hip_atomic_load(&(colPrev)[tid], __ATOMIC_RELAXED, \
                                            __HIP_MEMORY_SCOPE_AGENT) >= (nPrev)) ? 1 : 0; \
        __syncthreads(); \
        if (tid < 8) { \
            if (s_cok[4 * tid] && s_cok[4 * tid + 1] && s_cok[4 * tid + 2] && s_cok[4 * tid + 3]) \
                s_ok[tid] = 1; \
        } \
        __syncthreads(); \
        if (s_ok[gq]) break; \
        __builtin_amdgcn_s_sleep(8); \
    } }

    for (int t = blockIdx.x; t < total; t += gridDim.x) {
        // locate tile in level-ordered list
        int lev = 0;
        while (lev + 1 < nload && s_rbs[lev + 1] * NTILE <= t) ++lev;
        int lt = t - s_rbs[lev] * NTILE;
        int ntile = lt % NTILE;
        int mt = lt / NTILE;
        int start = s_off[lev];
        int cnt = s_off[lev + 1] - start;
        int jc = ntile * BN;
        int r0 = mt * BM;
        int tbx = ntile * KIT;        // Wimg x half: it 0..15
        int tbh = ntile * KIT + 16;   // Wimg h half: it 16..31

        if (tid < BM) {
            int r = r0 + tid;
            int node = (r < cnt) ? order[start + r] : -1;
            s_node[tid] = node;
            int p = (node >= 0) ? parent[node] : 0;
            s_par[tid] = p;
            float t0 = 0.f, t1 = 0.f;
            if (node >= 0) { t0 = type_mask[node * 2]; t1 = type_mask[node * 2 + 1]; }
            s_tm[tid][0] = t0; s_tm[tid][1] = t1;
        }
        if (tid < 32) s_cok[tid] = 0;
        if (tid < 8) s_ok[tid] = 0;
        __syncthreads();

        f32x4 acc[4][4];
#pragma unroll
        for (int m = 0; m < 4; ++m)
#pragma unroll
            for (int n = 0; n < 4; ++n) acc[m][n] = (f32x4)(0.f);

        // ---- x-GEMM (no dependencies): gathered input rows
        {
            const float* aBaseX[4];
#pragma unroll
            for (int m = 0; m < 4; ++m) {
                int nd = s_node[wr * 64 + m * 16 + l15];
                aBaseX[m] = inputs + (size_t)(nd < 0 ? 0 : nd) * DIM;
            }
            float4 xa0[4][2], xa1[4][2]; uint4 xb0[4], xb1[4];
            LDA_X(xa0, 0); LDB(xb0, tbx, 0);
#pragma unroll
            for (int ii = 0; ii < 8; ++ii) {
                int e = 2 * ii, o = e + 1;
                LDA_X(xa1, o); LDB(xb1, tbx, o);
                __builtin_amdgcn_s_setprio(1);
                COMP_X(xa0, xb0);
                __builtin_amdgcn_s_setprio(0);
                if (e + 2 < 16) { LDA_X(xa0, e + 2); LDB(xb0, tbx, e + 2); }
                __builtin_amdgcn_s_setprio(1);
                COMP_X(xa1, xb1);
                __builtin_amdgcn_s_setprio(0);
            }
        }

        // ---- h-GEMM: chase parent level's column wavefront (8 groups)
        if (lev > 0) {
            const int* colPrev = colCnt + (lev - 1) * NTILE;
            int nPrev = s_rbs[lev] - s_rbs[lev - 1];

            uint4 ha0[4][2], ha1[4][2]; uint4 hb0[4], hb1[4];
            LDB(hb0, tbh, 0); LDB(hb1, tbh, 1);   // B prefetch (no dep)

            WAIT_GROUPS(colPrev, nPrev, 0);       // parent ntiles 0..3 (iters 0,1)

            const uint_t* aBaseH[4];
#pragma unroll
            for (int m = 0; m < 4; ++m) {
                int p = s_par[wr * 64 + m * 16 + l15];
                aBaseH[m] = hPack + (size_t)((p > 0) ? (p - 1) : 0) * DIM;
            }
            LDA_H(ha0, 0); LDA_H(ha1, 1);
#pragma unroll
            for (int ii = 0; ii < 8; ++ii) {
                int e = 2 * ii, o = e + 1;
                __builtin_amdgcn_s_setprio(1);
                COMP_H(ha0, hb0);
                __builtin_amdgcn_s_setprio(0);
                if (ii < 7) {
                    if (!s_ok[ii + 1]) WAIT_GROUPS(colPrev, nPrev, ii + 1);
                    LDA_H(ha0, e + 2); LDB(hb0, tbh, e + 2);
                }
                __builtin_amdgcn_s_setprio(1);
                COMP_H(ha1, hb1);
                __builtin_amdgcn_s_setprio(0);
                if (ii < 7) { LDA_H(ha1, o + 2); LDB(hb1, tbh, o + 2); }
            }
        }

        // ---- epilogue: acc transpose + bias + LSTM cell + publish stores
        int cntloc = cnt - r0; if (cntloc > BM) cntloc = BM;
        __syncthreads();
#pragma unroll
        for (int pass = 0; pass < 2; ++pass) {
            if (wc == pass) {
#pragma unroll
                for (int m = 0; m < 4; ++m)
#pragma unroll
                    for (int n = 0; n < 4; ++n) {
                        int row = wr * 64 + m * 16 + g * 4;
                        int c = n * 16 + l15;
#pragma unroll
                        for (int r = 0; r < 4; ++r) eps[(row + r) * 68 + c] = acc[m][n][r];
                    }
            }
            __syncthreads();
#pragma unroll
            for (int e = 0; e < 4; ++e) {
                int task = e * 256 + tid;
                int row = task >> 3, dl = task & 7;
                if (row < cntloc) {
                    int node = s_node[row]; int p = s_par[row];
                    const float* ep = &eps[row * 68 + dl * 8];
                    float4 v0 = *(const float4*)ep;
                    float4 v1 = *(const float4*)(ep + 4);
                    int jb = jc + pass * 64 + dl * 8;
                    float4 b0 = *(const float4*)(bias + jb);
                    float4 b1 = *(const float4*)(bias + jb + 4);
                    int d = jb >> 3;
                    float cp = 0.f;
                    if (p > 0) {
                        uint_t wrd = cPack[(size_t)(p - 1) * DIM + d];
                        cp = __uint_as_float(wrd & 0xffff0000u) + __uint_as_float(wrd << 16);
                    }
                    float cv = sigm(v0.x + b0.x) * tanh_fast(v0.z + b0.z)
                             + sigm(v0.w + b0.w) * cp;
                    float hv = sigm(v0.y + b0.y) * tanh_fast(cv);
                    float cl = sigm(v1.x + b1.x) * tanh_fast(v1.z + b1.z)
                             + sigm(v1.w + b1.w) * cp;
                    float hl = sigm(v1.y + b1.y) * tanh_fast(cl);
                    float tm0 = s_tm[row][0], tm1 = s_tm[row][1];
                    float cn = tm0 * cl + tm1 * cv;
                    float hn2 = tm0 * hl + tm1 * hv;
                    size_t oi = (size_t)node * DIM + d;
                    __hip_atomic_store(&cPack[oi], packf(cn),
                                       __ATOMIC_RELAXED, __HIP_MEMORY_SCOPE_AGENT);
                    __hip_atomic_store(&hPack[oi], packf(hn2),
                                       __ATOMIC_RELAXED, __HIP_MEMORY_SCOPE_AGENT);
                    cOut[oi] = cn;
                    hOut[oi] = hn2;
                }
            }
            __syncthreads();
        }

        __builtin_amdgcn_s_waitcnt(0);   // drain this wave's sc1 stores
        __syncthreads();
        if (tid == 0)
            __hip_atomic_fetch_add(&colCnt[lev * NTILE + ntile], 1,
                                   __ATOMIC_RELAXED, __HIP_MEMORY_SCOPE_AGENT);
    }
#undef LDB
#undef LDA_H
#undef LDA_X
#undef COMP_H
#undef COMP_X
#undef WAIT_GROUPS
}

// ---------------------------------------------------------------------------
extern "C" void kernel_launch(void* const* d_in, const int* in_sizes, int n_in,
                              void* d_out, int out_size, void* d_ws, size_t ws_size,
                              hipStream_t stream) {
    const float* inputs      = (const float*)d_in[0];
    const float* type_mask   = (const float*)d_in[1];
    const int*   parent      = (const int*)d_in[2];
    const float* W_ioux_vis  = (const float*)d_in[3];
    const float* b_ioux_vis  = (const float*)d_in[4];
    const float* W_iouh_vis  = (const float*)d_in[5];
    const float* b_iouh_vis  = (const float*)d_in[6];
    const float* W_fx_vis    = (const float*)d_in[7];
    const float* b_fx_vis    = (const float*)d_in[8];
    const float* W_fh_vis    = (const float*)d_in[9];
    const float* b_fh_vis    = (const float*)d_in[10];
    const float* W_ioux_lang = (const float*)d_in[11];
    const float* b_ioux_lang = (const float*)d_in[12];
    const float* W_iouh_lang = (const float*)d_in[13];
    const float* b_iouh_lang = (const float*)d_in[14];
    const float* W_fx_lang   = (const float*)d_in[15];
    const float* b_fx_lang   = (const float*)d_in[16];
    const float* W_fh_lang   = (const float*)d_in[17];
    const float* b_fh_lang   = (const float*)d_in[18];

    ushort_t* Wimg = (ushort_t*)d_ws;                      // 8 MB
    float* bias    = (float*)(Wimg + WIMG_USHORTS);
    int* order     = (int*)(bias + NCOLS);
    int* offsets   = order + N_NODES;
    int* counts    = offsets + (N_NODES + 2);
    int* cursors   = counts + (N_NODES + 2);
    int* nlev      = cursors + (N_NODES + 2);
    int* tilestart = nlev + 8;
    int* rbStart   = tilestart + (N_NODES + 2);
    int* nodeHrb   = rbStart + (N_NODES + 2);
    int* colCnt    = nodeHrb + N_NODES;                    // MAXLEV_LDS*32 = 4096
    size_t off2 = (size_t)((char*)(colCnt + MAXLEV_LDS * NTILE) - (char*)d_ws);
    off2 = (off2 + 255) & ~(size_t)255;
    uint_t* hPack = (uint_t*)((char*)d_ws + off2);                       // 16 MB
    uint_t* cPack = hPack + (size_t)N_NODES * DIM;                       // 16 MB

    float* out = (float*)d_out;

    hipMemsetAsync((void*)colCnt, 0, MAXLEV_LDS * NTILE * sizeof(int), stream);

    hipLaunchKernelGGL(prep_wimg_kernel, dim3(NTILE * KIT), dim3(256), 0, stream,
                       W_ioux_vis, W_iouh_vis, W_fx_vis, W_fh_vis,
                       W_ioux_lang, W_iouh_lang, W_fx_lang, W_fh_lang, Wimg);
    hipLaunchKernelGGL(prep_bias_kernel, dim3(NCOLS / 256), dim3(256), 0, stream,
                       b_ioux_vis, b_iouh_vis, b_fx_vis, b_fh_vis,
                       b_ioux_lang, b_iouh_lang, b_fx_lang, b_fh_lang, bias);
    hipLaunchKernelGGL(levels_sort_kernel, dim3(1), dim3(1024), 0, stream,
                       parent, order, offsets, counts, cursors, nlev, tilestart,
                       rbStart, nodeHrb);

    int occ = 0;
    if (hipOccupancyMaxActiveBlocksPerMultiprocessor(&occ, (const void*)tree_fused_kernel, 256, 0) != hipSuccess || occ < 1)
        occ = 1;
    int bpc = occ < 2 ? occ : 2;
    dim3 grid(256 * bpc);

    void* args[] = { (void*)&inputs, (void*)&type_mask, (void*)&Wimg, (void*)&bias,
                     (void*)&order, (void*)&offsets, (void*)&nlev, (void*)&parent,
                     (void*)&rbStart, (void*)&colCnt,
                     (void*)&hPack, (void*)&cPack, (void*)&out };
    hipLaunchCooperativeKernel((const void*)tree_fused_kernel, grid, dim3(256), args, 0, stream);
}

// Round 12
// 807.782 us; speedup vs baseline: 1.6302x; 1.0091x over previous
//
#include <hip/hip_runtime.h>
#include <math.h>

typedef unsigned short ushort_t;
typedef unsigned int uint_t;
typedef unsigned long long u64_t;
typedef __attribute__((ext_vector_type(8))) short short8;
typedef __attribute__((ext_vector_type(4))) float f32x4;

#define N_NODES 8192
#define DIM 512
#define KTOT 1024
#define NCOLS 4096
#define BM 128
#define BN 128
#define NTILE (NCOLS / BN)   // 32 column tiles
#define KIT (KTOT / 32)      // 32 k iterations (BK=32)
// Wimg: hi-plane bf16, direct-fragment layout: tile(ntile,it) 128 cols x 32 k
#define WIMG_USHORTS ((size_t)NTILE * KIT * 4096)
#define MAXLEV_LDS 128

__device__ __forceinline__ float sigm(float x) { return 1.0f / (1.0f + __expf(-x)); }
__device__ __forceinline__ float tanh_fast(float x) {
    float ax = fabsf(x);
    float e = __expf(2.0f * ax);
    float t = 1.0f - 2.0f / (e + 1.0f);
    return copysignf(t, x);
}
__device__ __forceinline__ uint_t packf(float f) {
    uint_t u = __float_as_uint(f);
    uint_t hi = u & 0xffff0000u;
    float r = f - __uint_as_float(hi);
    return hi | (__float_as_uint(r) >> 16);
}
__device__ __forceinline__ float unpackw(uint_t w) {
    return __uint_as_float(w & 0xffff0000u) + __uint_as_float(w << 16);
}
__device__ __forceinline__ uint_t rne16(float f) {
    uint_t u = __float_as_uint(f);
    return (u + 0x7fffu + ((u >> 16) & 1u)) >> 16;
}

// split 8 packed (hi|lo) u32 -> hi-frag / lo-frag short8
__device__ __forceinline__ void fragAB_u32(const uint4 w0, const uint4 w1,
                                           short8& hi8, short8& lo8) {
    union { uint_t w[4]; short8 s; } H, L;
    uint_t u[8] = { w0.x, w0.y, w0.z, w0.w, w1.x, w1.y, w1.z, w1.w };
#pragma unroll
    for (int j = 0; j < 4; ++j) {
        H.w[j] = (u[2 * j + 1] & 0xffff0000u) | (u[2 * j] >> 16);
        L.w[j] = (u[2 * j + 1] << 16) | (u[2 * j] & 0xffffu);
    }
    hi8 = H.s; lo8 = L.s;
}

// split 8 fp32 -> hi-frag (trunc) / lo-frag (residual) short8
__device__ __forceinline__ void fragA_f32(const float4 f0, const float4 f1,
                                          short8& hi8, short8& lo8) {
    union { uint_t w[4]; short8 s; } H, L;
    float f[8] = { f0.x, f0.y, f0.z, f0.w, f1.x, f1.y, f1.z, f1.w };
#pragma unroll
    for (int j = 0; j < 4; ++j) {
        float a = f[2 * j], b = f[2 * j + 1];
        uint_t h0 = __float_as_uint(a) & 0xffff0000u;
        uint_t h1 = __float_as_uint(b) & 0xffff0000u;
        float r0 = a - __uint_as_float(h0);
        float r1 = b - __uint_as_float(h1);
        H.w[j] = h1 | (h0 >> 16);
        L.w[j] = (__float_as_uint(r1) & 0xffff0000u) | (__float_as_uint(r0) >> 16);
    }
    hi8 = H.s; lo8 = L.s;
}

// ---------------------------------------------------------------------------
// Prep: weights -> bf16 (hi plane, RNE), direct-fragment image (verified r8-r11)
// ---------------------------------------------------------------------------
__global__ void __launch_bounds__(256) prep_wimg_kernel(
    const float* __restrict__ Wx_iou_v, const float* __restrict__ Wh_iou_v,
    const float* __restrict__ Wx_f_v,   const float* __restrict__ Wh_f_v,
    const float* __restrict__ Wx_iou_l, const float* __restrict__ Wh_iou_l,
    const float* __restrict__ Wx_f_l,   const float* __restrict__ Wh_f_l,
    ushort_t* __restrict__ Wimg)
{
    __shared__ float T[32][132];   // T[kk][jloc]
    int p = blockIdx.x >> 5, it = blockIdx.x & 31;
    int tid = threadIdx.x;
#pragma unroll
    for (int e = 0; e < 16; ++e) {
        int lin = e * 256 + tid;
        int dloc = lin & 15, kk = (lin >> 4) & 31, q = lin >> 9;
        int d = p * 16 + dloc;
        int qq = q & 3; bool lang = q >= 4;
        int k = it * 32 + kk;
        const float* W; int col, stride;
        if (qq < 3) { col = qq * DIM + d; stride = 3 * DIM;
            W = (k < DIM) ? (lang ? Wx_iou_l : Wx_iou_v) : (lang ? Wh_iou_l : Wh_iou_v); }
        else        { col = d; stride = DIM;
            W = (k < DIM) ? (lang ? Wx_f_l : Wx_f_v) : (lang ? Wh_f_l : Wh_f_v); }
        int kr = (k < DIM) ? k : (k - DIM);
        T[kk][dloc * 8 + q] = W[(size_t)kr * stride + col];
    }
    __syncthreads();
    size_t tilebase = (size_t)blockIdx.x * 4096;
#pragma unroll
    for (int gch = 0; gch < 2; ++gch) {
        int gi = gch * 256 + tid;          // uint4 index 0..511
        int col = gi >> 2, gd = gi & 3;
        uint_t wds[4];
#pragma unroll
        for (int i = 0; i < 4; ++i) {
            uint_t v0 = rne16(T[gd * 8 + 2 * i][col]);
            uint_t v1 = rne16(T[gd * 8 + 2 * i + 1][col]);
            wds[i] = (v1 << 16) | v0;
        }
        *(uint4*)(Wimg + tilebase + (size_t)gi * 8) = make_uint4(wds[0], wds[1], wds[2], wds[3]);
    }
}

__global__ void prep_bias_kernel(
    const float* __restrict__ bx_iou_v, const float* __restrict__ bh_iou_v,
    const float* __restrict__ bx_f_v,   const float* __restrict__ bh_f_v,
    const float* __restrict__ bx_iou_l, const float* __restrict__ bh_iou_l,
    const float* __restrict__ bx_f_l,   const float* __restrict__ bh_f_l,
    float* __restrict__ bias)
{
    int j = blockIdx.x * blockDim.x + threadIdx.x;
    if (j >= NCOLS) return;
    int d = j >> 3, q = j & 7;
    int qq = q & 3;
    bool lang = (q & 4) != 0;
    const float* bx; const float* bh; int col;
    if (qq < 3) { col = qq * DIM + d; bx = lang ? bx_iou_l : bx_iou_v; bh = lang ? bh_iou_l : bh_iou_v; }
    else        { col = d;            bx = lang ? bx_f_l  : bx_f_v;   bh = lang ? bh_f_l  : bh_f_v; }
    bias[j] = bx[col] + bh[col];
}

// ---------------------------------------------------------------------------
// Level computation + counting sort + rowblock tables (verified r4-r11)
// ---------------------------------------------------------------------------
__global__ void __launch_bounds__(1024) levels_sort_kernel(
    const int* __restrict__ parent,
    int* __restrict__ order, int* __restrict__ offsets,
    int* __restrict__ counts, int* __restrict__ cursors,
    int* __restrict__ nlev, int* __restrict__ tilestart,
    int* __restrict__ rbStart, int* __restrict__ nodeHrb)
{
    __shared__ int s_level[N_NODES];
    __shared__ int s_assigned;
    __shared__ int s_maxlev;
    int tid = threadIdx.x;
    int pr[8];
#pragma unroll
    for (int ii = 0; ii < 8; ++ii) {
        int i = tid + ii * 1024;
        pr[ii] = parent[i];
        s_level[i] = -1;
    }
    for (int i = tid; i <= N_NODES; i += 1024) counts[i] = 0;
    if (tid == 0) { s_assigned = 0; s_maxlev = 0; }
    __syncthreads();

    for (int pass = 0; pass <= N_NODES; ++pass) {
        int newly = 0;
#pragma unroll
        for (int ii = 0; ii < 8; ++ii) {
            int i = tid + ii * 1024;
            if (s_level[i] < 0) {
                int p = pr[ii];
                if (p == 0) { s_level[i] = 0; newly++; }
                else { int lp = s_level[p - 1]; if (lp >= 0) { s_level[i] = lp + 1; newly++; } }
            }
        }
        if (newly) atomicAdd(&s_assigned, newly);
        __syncthreads();
        int a = s_assigned;
        if (a >= N_NODES) break;
        __syncthreads();
    }

#pragma unroll
    for (int ii = 0; ii < 8; ++ii) {
        int i = tid + ii * 1024;
        int lv = s_level[i];
        atomicAdd(&counts[lv], 1);
        atomicMax(&s_maxlev, lv);
    }
    __syncthreads();
    if (tid == 0) {
        int nl = s_maxlev + 1;
        nlev[0] = nl;
        int off = 0, toff = 0, rb = 0;
        for (int l = 0; l < nl; ++l) {
            offsets[l] = off; cursors[l] = off;
            tilestart[l] = toff; rbStart[l] = rb;
            int mt = (counts[l] + BM - 1) / BM;
            rb += mt;
            toff += mt * NTILE;
            off += counts[l];
        }
        offsets[nl] = off;
        tilestart[nl] = toff;
        rbStart[nl] = rb;
        nlev[1] = toff;   // total fused tiles
    }
    __syncthreads();
#pragma unroll
    for (int ii = 0; ii < 8; ++ii) {
        int i = tid + ii * 1024;
        int lv = s_level[i];
        int pos = atomicAdd(&cursors[lv], 1);
        order[pos] = i;
        nodeHrb[i] = rbStart[lv] + ((pos - offsets[lv]) >> 7);
    }
}

// ---------------------------------------------------------------------------
// Fused worker (r11 base) + rotated k-start + single-pass epilogue +
// publish-before-output.
// ---------------------------------------------------------------------------
__global__ void __launch_bounds__(256, 2) tree_fused_kernel(
    const float* __restrict__ inputs, const float* __restrict__ type_mask,
    const ushort_t* __restrict__ Wimg, const float* __restrict__ bias,
    const int* __restrict__ order, const int* __restrict__ offsets,
    const int* __restrict__ nlev, const int* __restrict__ parent,
    const int* __restrict__ rbStart,
    int* __restrict__ colCnt,
    uint_t* __restrict__ hPack, uint_t* __restrict__ cPack,
    float* __restrict__ out)
{
    float* cOut = out;
    float* hOut = out + (size_t)N_NODES * DIM;

    __shared__ float eps[BM * 132];      // 67.6 KB single-pass transpose
    __shared__ int s_node[BM];
    __shared__ int s_par[BM];
    __shared__ float s_tm[BM][2];
    __shared__ int s_rbs[MAXLEV_LDS];
    __shared__ int s_off[MAXLEV_LDS];
    __shared__ int s_cok[32];
    __shared__ int s_ok[8];

    int tid = threadIdx.x;
    int lane = tid & 63, w = tid >> 6, wr = w >> 1, wc = w & 1;
    int l15 = lane & 15, g = lane >> 4;
    int nl = nlev[0];
    int total = nlev[1];

    int nload = nl + 1; if (nload > MAXLEV_LDS) nload = MAXLEV_LDS;
    for (int i = tid; i < nload; i += 256) { s_rbs[i] = rbStart[i]; s_off[i] = offsets[i]; }
    __syncthreads();

    // B fragment base for this lane (ushort units); tile stride 4096, n stride 512
    const ushort_t* bLane = Wimg + (size_t)(wc * 64 + l15) * 32 + (size_t)g * 8;

#define LDB(RB, tilebase, itt) { \
    _Pragma("unroll") for (int n_ = 0; n_ < 4; ++n_) \
        RB[n_] = *(const uint4*)(bLane + (size_t)(tilebase + (itt)) * 4096 + n_ * 512); }

#define LDA_H(RA, itrel) { \
    _Pragma("unroll") for (int m_ = 0; m_ < 4; ++m_) { \
        const uint4* p_ = (const uint4*)(aBaseH[m_] + (itrel) * 32 + g * 8); \
        RA[m_][0] = p_[0]; RA[m_][1] = p_[1]; } }

#define LDA_X(RA, itt) { \
    _Pragma("unroll") for (int m_ = 0; m_ < 4; ++m_) { \
        const float4* p_ = (const float4*)(aBaseX[m_] + (itt) * 32 + g * 8); \
        RA[m_][0] = p_[0]; RA[m_][1] = p_[1]; } }

#define COMP_H(RA, RB) { \
    short8 bh_[4]; \
    _Pragma("unroll") for (int n_ = 0; n_ < 4; ++n_) { \
        union { uint4 u; short8 s; } c_; c_.u = RB[n_]; bh_[n_] = c_.s; } \
    _Pragma("unroll") for (int m_ = 0; m_ < 4; ++m_) { \
        short8 ah_, al_; fragAB_u32(RA[m_][0], RA[m_][1], ah_, al_); \
        _Pragma("unroll") for (int n_ = 0; n_ < 4; ++n_) { \
            acc[m_][n_] = __builtin_amdgcn_mfma_f32_16x16x32_bf16(ah_, bh_[n_], acc[m_][n_], 0, 0, 0); \
            acc[m_][n_] = __builtin_amdgcn_mfma_f32_16x16x32_bf16(al_, bh_[n_], acc[m_][n_], 0, 0, 0); } } }

#define COMP_X(RA, RB) { \
    short8 bh_[4]; \
    _Pragma("unroll") for (int n_ = 0; n_ < 4; ++n_) { \
        union { uint4 u; short8 s; } c_; c_.u = RB[n_]; bh_[n_] = c_.s; } \
    _Pragma("unroll") for (int m_ = 0; m_ < 4; ++m_) { \
        short8 ah_, al_; fragA_f32(RA[m_][0], RA[m_][1], ah_, al_); \
        _Pragma("unroll") for (int n_ = 0; n_ < 4; ++n_) { \
            acc[m_][n_] = __builtin_amdgcn_mfma_f32_16x16x32_bf16(ah_, bh_[n_], acc[m_][n_], 0, 0, 0); \
            acc[m_][n_] = __builtin_amdgcn_mfma_f32_16x16x32_bf16(al_, bh_[n_], acc[m_][n_], 0, 0, 0); } } }

// barrier-disciplined wait for column group gq (parent ntiles [4gq,4gq+4))
#define WAIT_GROUPS(colPrev, nPrev, gq) { \
    for (;;) { \
        if (tid < 32) \
            s_cok[tid] = (__hip_atomic_load(&(colPrev)[tid], __ATOMIC_RELAXED, \
                                            __HIP_MEMORY_SCOPE_AGENT) >= (nPrev)) ? 1 : 0; \
        __syncthreads(); \
        if (tid < 8) { \
            if (s_cok[4 * tid] && s_cok[4 * tid + 1] && s_cok[4 * tid + 2] && s_cok[4 * tid + 3]) \
                s_ok[tid] = 1; \
        } \
        __syncthreads(); \
        if (s_ok[gq]) break; \
        __builtin_amdgcn_s_sleep(4); \
    } }

    for (int t = blockIdx.x; t < total; t += gridDim.x) {
        // locate tile in level-ordered list
        int lev = 0;
        while (lev + 1 < nload && s_rbs[lev + 1] * NTILE <= t) ++lev;
        int lt = t - s_rbs[lev] * NTILE;
        int ntile = lt % NTILE;
        int mt = lt / NTILE;
        int start = s_off[lev];
        int cnt = s_off[lev + 1] - start;
        int jc = ntile * BN;
        int r0 = mt * BM;
        int tbx = ntile * KIT;        // Wimg x half: it 0..15
        int tbh = ntile * KIT + 16;   // Wimg h half: it 16..31

        if (tid < BM) {
            int r = r0 + tid;
            int node = (r < cnt) ? order[start + r] : -1;
            s_node[tid] = node;
            int p = (node >= 0) ? parent[node] : 0;
            s_par[tid] = p;
            float t0 = 0.f, t1 = 0.f;
            if (node >= 0) { t0 = type_mask[node * 2]; t1 = type_mask[node * 2 + 1]; }
            s_tm[tid][0] = t0; s_tm[tid][1] = t1;
        }
        if (tid < 32) s_cok[tid] = 0;
        if (tid < 8) s_ok[tid] = 0;
        __syncthreads();

        f32x4 acc[4][4];
#pragma unroll
        for (int m = 0; m < 4; ++m)
#pragma unroll
            for (int n = 0; n < 4; ++n) acc[m][n] = (f32x4)(0.f);

        // ---- x-GEMM (no dependencies): gathered input rows
        {
            const float* aBaseX[4];
#pragma unroll
            for (int m = 0; m < 4; ++m) {
                int nd = s_node[wr * 64 + m * 16 + l15];
                aBaseX[m] = inputs + (size_t)(nd < 0 ? 0 : nd) * DIM;
            }
            float4 xa0[4][2], xa1[4][2]; uint4 xb0[4], xb1[4];
            LDA_X(xa0, 0); LDB(xb0, tbx, 0);
#pragma unroll
            for (int ii = 0; ii < 8; ++ii) {
                int e = 2 * ii, o = e + 1;
                LDA_X(xa1, o); LDB(xb1, tbx, o);
                __builtin_amdgcn_s_setprio(1);
                COMP_X(xa0, xb0);
                __builtin_amdgcn_s_setprio(0);
                if (e + 2 < 16) { LDA_X(xa0, e + 2); LDB(xb0, tbx, e + 2); }
                __builtin_amdgcn_s_setprio(1);
                COMP_X(xa1, xb1);
                __builtin_amdgcn_s_setprio(0);
            }
        }

        // ---- h-GEMM: rotated-group chase of parent level's column wavefront
        if (lev > 0) {
            const int* colPrev = colCnt + (lev - 1) * NTILE;
            int nPrev = s_rbs[lev] - s_rbs[lev - 1];
            const int gb = ntile >> 2;   // rotated start group

            const uint_t* aBaseH[4];
#pragma unroll
            for (int m = 0; m < 4; ++m) {
                int p = s_par[wr * 64 + m * 16 + l15];
                aBaseH[m] = hPack + (size_t)((p > 0) ? (p - 1) : 0) * DIM;
            }

            uint4 ha0[4][2], ha1[4][2]; uint4 hb0[4], hb1[4];
            WAIT_GROUPS(colPrev, nPrev, gb);
            LDA_H(ha0, 2 * gb); LDB(hb0, tbh, 2 * gb);
            LDA_H(ha1, 2 * gb + 1); LDB(hb1, tbh, 2 * gb + 1);
#pragma unroll
            for (int s = 0; s < 8; ++s) {
                const int gn = (gb + s + 1) & 7;
                __builtin_amdgcn_s_setprio(1);
                COMP_H(ha0, hb0);
                __builtin_amdgcn_s_setprio(0);
                if (s < 7) {
                    if (!s_ok[gn]) WAIT_GROUPS(colPrev, nPrev, gn);
                    LDA_H(ha0, 2 * gn); LDB(hb0, tbh, 2 * gn);
                }
                __builtin_amdgcn_s_setprio(1);
                COMP_H(ha1, hb1);
                __builtin_amdgcn_s_setprio(0);
                if (s < 7) { LDA_H(ha1, 2 * gn + 1); LDB(hb1, tbh, 2 * gn + 1); }
            }
        }

        // ---- single-pass epilogue ----
        int cntloc = cnt - r0; if (cntloc > BM) cntloc = BM;

        // (1) early cPack gather (gate: parent col==ntile, satisfied by k-waits)
        float CP[8];
#pragma unroll
        for (int e = 0; e < 8; ++e) {
            int task = e * 256 + tid;         // 0..2047
            int row = task >> 4, dl = task & 15;
            CP[e] = 0.f;
            if (row < cntloc) {
                int p = s_par[row];
                if (p > 0) {
                    int d = (jc + dl * 8) >> 3;
                    CP[e] = unpackw(cPack[(size_t)(p - 1) * DIM + d]);
                }
            }
        }

        // (2) full transpose (each wave its own quadrant; disjoint writes)
#pragma unroll
        for (int m = 0; m < 4; ++m)
#pragma unroll
            for (int n = 0; n < 4; ++n) {
                int row = wr * 64 + m * 16 + g * 4;
                int c = wc * 64 + n * 16 + l15;
#pragma unroll
                for (int r = 0; r < 4; ++r) eps[(row + r) * 132 + c] = acc[m][n][r];
            }
        __syncthreads();

        // (3) LSTM cell; sc1 publish stores first, outputs retained in regs
        float CN[8], HN[8];
#pragma unroll
        for (int e = 0; e < 8; ++e) {
            int task = e * 256 + tid;
            int row = task >> 4, dl = task & 15;
            CN[e] = 0.f; HN[e] = 0.f;
            if (row < cntloc) {
                int node = s_node[row];
                const float* ep = &eps[row * 132 + dl * 8];
                float4 v0 = *(const float4*)ep;
                float4 v1 = *(const float4*)(ep + 4);
                int jb = jc + dl * 8;
                float4 b0 = *(const float4*)(bias + jb);
                float4 b1 = *(const float4*)(bias + jb + 4);
                float cp = CP[e];
                float cv = sigm(v0.x + b0.x) * tanh_fast(v0.z + b0.z)
                         + sigm(v0.w + b0.w) * cp;
                float hv = sigm(v0.y + b0.y) * tanh_fast(cv);
                float cl = sigm(v1.x + b1.x) * tanh_fast(v1.z + b1.z)
                         + sigm(v1.w + b1.w) * cp;
                float hl = sigm(v1.y + b1.y) * tanh_fast(cl);
                float tm0 = s_tm[row][0], tm1 = s_tm[row][1];
                float cn = tm0 * cl + tm1 * cv;
                float hn2 = tm0 * hl + tm1 * hv;
                CN[e] = cn; HN[e] = hn2;
                size_t oi = (size_t)node * DIM + (jb >> 3);
                __hip_atomic_store(&cPack[oi], packf(cn),
                                   __ATOMIC_RELAXED, __HIP_MEMORY_SCOPE_AGENT);
                __hip_atomic_store(&hPack[oi], packf(hn2),
                                   __ATOMIC_RELAXED, __HIP_MEMORY_SCOPE_AGENT);
            }
        }

        // (4) drain sc1 stores, publish, THEN write plain outputs
        __builtin_amdgcn_s_waitcnt(0);
        __syncthreads();
        if (tid == 0)
            __hip_atomic_fetch_add(&colCnt[lev * NTILE + ntile], 1,
                                   __ATOMIC_RELAXED, __HIP_MEMORY_SCOPE_AGENT);

#pragma unroll
        for (int e = 0; e < 8; ++e) {
            int task = e * 256 + tid;
            int row = task >> 4, dl = task & 15;
            if (row < cntloc) {
                int node = s_node[row];
                size_t oi = (size_t)node * DIM + ((jc + dl * 8) >> 3);
                cOut[oi] = CN[e];
                hOut[oi] = HN[e];
            }
        }
        __syncthreads();   // protect s_node/s_par before next tile overwrites
    }
#undef LDB
#undef LDA_H
#undef LDA_X
#undef COMP_H
#undef COMP_X
#undef WAIT_GROUPS
}

// ---------------------------------------------------------------------------
extern "C" void kernel_launch(void* const* d_in, const int* in_sizes, int n_in,
                              void* d_out, int out_size, void* d_ws, size_t ws_size,
                              hipStream_t stream) {
    const float* inputs      = (const float*)d_in[0];
    const float* type_mask   = (const float*)d_in[1];
    const int*   parent      = (const int*)d_in[2];
    const float* W_ioux_vis  = (const float*)d_in[3];
    const float* b_ioux_vis  = (const float*)d_in[4];
    const float* W_iouh_vis  = (const float*)d_in[5];
    const float* b_iouh_vis  = (const float*)d_in[6];
    const float* W_fx_vis    = (const float*)d_in[7];
    const float* b_fx_vis    = (const float*)d_in[8];
    const float* W_fh_vis    = (const float*)d_in[9];
    const float* b_fh_vis    = (const float*)d_in[10];
    const float* W_ioux_lang = (const float*)d_in[11];
    const float* b_ioux_lang = (const float*)d_in[12];
    const float* W_iouh_lang = (const float*)d_in[13];
    const float* b_iouh_lang = (const float*)d_in[14];
    const float* W_fx_lang   = (const float*)d_in[15];
    const float* b_fx_lang   = (const float*)d_in[16];
    const float* W_fh_lang   = (const float*)d_in[17];
    const float* b_fh_lang   = (const float*)d_in[18];

    ushort_t* Wimg = (ushort_t*)d_ws;                      // 8 MB
    float* bias    = (float*)(Wimg + WIMG_USHORTS);
    int* order     = (int*)(bias + NCOLS);
    int* offsets   = order + N_NODES;
    int* counts    = offsets + (N_NODES + 2);
    int* cursors   = counts + (N_NODES + 2);
    int* nlev      = cursors + (N_NODES + 2);
    int* tilestart = nlev + 8;
    int* rbStart   = tilestart + (N_NODES + 2);
    int* nodeHrb   = rbStart + (N_NODES + 2);
    int* colCnt    = nodeHrb + N_NODES;                    // MAXLEV_LDS*32 = 4096
    size_t off2 = (size_t)((char*)(colCnt + MAXLEV_LDS * NTILE) - (char*)d_ws);
    off2 = (off2 + 255) & ~(size_t)255;
    uint_t* hPack = (uint_t*)((char*)d_ws + off2);                       // 16 MB
    uint_t* cPack = hPack + (size_t)N_NODES * DIM;                       // 16 MB

    float* out = (float*)d_out;

    hipMemsetAsync((void*)colCnt, 0, MAXLEV_LDS * NTILE * sizeof(int), stream);

    hipLaunchKernelGGL(prep_wimg_kernel, dim3(NTILE * KIT), dim3(256), 0, stream,
                       W_ioux_vis, W_iouh_vis, W_fx_vis, W_fh_vis,
                       W_ioux_lang, W_iouh_lang, W_fx_lang, W_fh_lang, Wimg);
    hipLaunchKernelGGL(prep_bias_kernel, dim3(NCOLS / 256), dim3(256), 0, stream,
                       b_ioux_vis, b_iouh_vis, b_fx_vis, b_fh_vis,
                       b_ioux_lang, b_iouh_lang, b_fx_lang, b_fh_lang, bias);
    hipLaunchKernelGGL(levels_sort_kernel, dim3(1), dim3(1024), 0, stream,
                       parent, order, offsets, counts, cursors, nlev, tilestart,
                       rbStart, nodeHrb);

    int occ = 0;
    if (hipOccupancyMaxActiveBlocksPerMultiprocessor(&occ, (const void*)tree_fused_kernel, 256, 0) != hipSuccess || occ < 1)
        occ = 1;
    int bpc = occ < 2 ? occ : 2;
    dim3 grid(256 * bpc);

    void* args[] = { (void*)&inputs, (void*)&type_mask, (void*)&Wimg, (void*)&bias,
                     (void*)&order, (void*)&offsets, (void*)&nlev, (void*)&parent,
                     (void*)&rbStart, (void*)&colCnt,
                     (void*)&hPack, (void*)&cPack, (void*)&out };
    hipLaunchCooperativeKernel((const void*)tree_fused_kernel, grid, dim3(256), args, 0, stream);
}